// Round 5
// baseline (372.549 us; speedup 1.0000x reference)
//
#include <hip/hip_runtime.h>
#include <math.h>

#define N_NODES 100000
#define F_IN    128
#define H1      8
#define C1      16
#define D1      128   // H1*C1
#define NCLS    40
#define NEG     0.2f

typedef unsigned int uint32;
typedef unsigned short ushort16;
typedef float v2f __attribute__((ext_vector_type(2)));
typedef __attribute__((ext_vector_type(8))) short bf16x8;   // 4 VGPRs, MFMA A/B frag
typedef __attribute__((ext_vector_type(4))) float f32x4;    // MFMA C/D frag

__device__ __forceinline__ ushort16 f2bf(float f) {
    unsigned int u = __float_as_uint(f);
    u += 0x7fffu + ((u >> 16) & 1u);          // round-to-nearest-even
    return (ushort16)(u >> 16);
}
__device__ __forceinline__ float bf_lo(uint32 p) { return __uint_as_float(p << 16); }
__device__ __forceinline__ float bf_hi(uint32 p) { return __uint_as_float(p & 0xffff0000u); }

#define NG  1563   // gemm blocks (64 rows each)
#define NCB 781    // count blocks (2048 edges each, 8/thread, grid-stride tail)

// W1 -> bf16 transposed+padded [128][136]; also zeroes deg (replaces memset).
__global__ void prep_w1_kernel(const float* __restrict__ W,
                               unsigned short* __restrict__ w1t,
                               int* __restrict__ deg)
{
    int idx = blockIdx.x * 256 + threadIdx.x;
    if (idx < 16384) {
        int n = idx & 127, k = idx >> 7;        // coalesced read of W[k][n]
        w1t[n * 136 + k] = f2bf(W[k * 128 + n]);
    }
    if (idx < N_NODES) deg[idx] = 0;
}

// ---------------- fused: layer-1 MFMA GEMM(+logits) blocks + CSR-count ------
// Period-3 interleave: bid%3==2 -> count block (8 edges/thread = 8 atomics
// in flight per lane), else gemm block. Count blocks co-resident with
// LDS/MFMA-bound gemm blocks from t=0.
__global__ __launch_bounds__(256) void gemm1_count_kernel(
    const float* __restrict__ x, const unsigned short* __restrict__ w1t,
    uint32* __restrict__ h8,            // fp8 rows, N x 32 dwords
    const float* __restrict__ a_src, const float* __restrict__ a_dst,
    float* __restrict__ ssrc, float* __restrict__ sdst,
    const int* __restrict__ ei, int E,
    int* __restrict__ deg, int* __restrict__ rank)
{
    // 34816 B: holds W1^T bf16 [128][136] during MFMA, then hs fp32 [64][132]
    __shared__ __align__(16) uint32 wbuf[8704];
    const int bid = blockIdx.x;
    const int tid = threadIdx.x;
    if ((bid % 3) == 2) {
        // ---------------- count path: rank[e] = old deg[dst]++ --------------
        const int cid = bid / 3;
        const int nspans = (E + 2047) >> 11;
        for (int sp = cid; sp < nspans; sp += NCB) {
            const long long base = (long long)sp << 11;
            int dd[8];
#pragma unroll
            for (int k = 0; k < 8; ++k) {
                long long e = base + tid + (k << 8);
                dd[k] = (e < E) ? ei[E + e] : -1;
            }
            int rk[8];
#pragma unroll
            for (int k = 0; k < 8; ++k)
                if (dd[k] >= 0) rk[k] = atomicAdd(&deg[dd[k]], 1);
#pragma unroll
            for (int k = 0; k < 8; ++k) {
                long long e = base + tid + (k << 8);
                if (e < E) rank[e] = rk[k];
            }
        }
        return;
    }
    const int gidx = (bid / 3) * 2 + (bid % 3);   // 0..NG-1
    const int row0 = gidx * 64;
    const int wid = tid >> 6, lane = tid & 63;

    // ---- A fragments straight from global: wave w owns rows 16w..16w+15.
    const int arow = row0 + wid * 16 + (lane & 15);
    const bool rowok = arow < N_NODES;
    const float* xp = x + (size_t)arow * 128 + 8 * (lane >> 4);
    float4 af0[4], af1[4];
#pragma unroll
    for (int s = 0; s < 4; ++s) {
        if (rowok) {
            af0[s] = *(const float4*)(xp + 32 * s);
            af1[s] = *(const float4*)(xp + 32 * s + 4);
        } else {
            af0[s] = make_float4(0.f, 0.f, 0.f, 0.f);
            af1[s] = make_float4(0.f, 0.f, 0.f, 0.f);
        }
    }
    // ---- stage W1^T bf16 into LDS (linear 34816 B copy, pad included) ----
    {
        const uint32* g = (const uint32*)w1t;
#pragma unroll
        for (int i = 0; i < 8; ++i)
            ((uint4*)wbuf)[tid + i * 256] = ((const uint4*)g)[tid + i * 256];
        wbuf[8192 + tid] = g[8192 + tid];
        wbuf[8448 + tid] = g[8448 + tid];
    }
    // ---- convert A to bf16 fragments (same k-order as B reads: 8g+j) ----
    bf16x8 a[4];
#pragma unroll
    for (int s = 0; s < 4; ++s) {
        a[s][0] = (short)f2bf(af0[s].x); a[s][1] = (short)f2bf(af0[s].y);
        a[s][2] = (short)f2bf(af0[s].z); a[s][3] = (short)f2bf(af0[s].w);
        a[s][4] = (short)f2bf(af1[s].x); a[s][5] = (short)f2bf(af1[s].y);
        a[s][6] = (short)f2bf(af1[s].z); a[s][7] = (short)f2bf(af1[s].w);
    }
    __syncthreads();
    // ---- K loop: 4 steps x 8 col-fragments = 32 MFMAs / wave ----
    f32x4 acc[8];
#pragma unroll
    for (int j = 0; j < 8; ++j)
#pragma unroll
        for (int r = 0; r < 4; ++r) acc[j][r] = 0.f;
    const unsigned short* wb = (const unsigned short*)wbuf;
    const int bc = lane & 15, ko = 8 * (lane >> 4);
#pragma unroll
    for (int s = 0; s < 4; ++s) {
#pragma unroll
        for (int j = 0; j < 8; ++j) {
            bf16x8 b = *(const bf16x8*)&wb[(16 * j + bc) * 136 + 32 * s + ko];
            acc[j] = __builtin_amdgcn_mfma_f32_16x16x32_bf16(a[s], b, acc[j], 0, 0, 0);
        }
    }
    __syncthreads();   // all MFMA operand reads of wbuf done
    // ---- write acc to hs[64][132] (C/D map: col=lane&15, row=(lane>>4)*4+r)
    float* hs = (float*)wbuf;
    const int cr0 = wid * 16 + 4 * (lane >> 4);
#pragma unroll
    for (int j = 0; j < 8; ++j)
#pragma unroll
        for (int r = 0; r < 4; ++r)
            hs[(cr0 + r) * 132 + 16 * j + bc] = acc[j][r];
    __syncthreads();
    // ---- fp8 pack: 64 rows x 16 uint2-groups, 4 tasks/thread ----
#pragma unroll
    for (int t = 0; t < 4; ++t) {
        int task = tid + t * 256;     // 0..1023
        int r = task >> 4, g = task & 15;
        if (row0 + r < N_NODES) {
            float4 va = *(const float4*)&hs[r * 132 + 8 * g];
            float4 vb = *(const float4*)&hs[r * 132 + 8 * g + 4];
            int p0 = __builtin_amdgcn_cvt_pk_fp8_f32(va.x, va.y, 0, false);
            p0     = __builtin_amdgcn_cvt_pk_fp8_f32(va.z, va.w, p0, true);
            int p1 = __builtin_amdgcn_cvt_pk_fp8_f32(vb.x, vb.y, 0, false);
            p1     = __builtin_amdgcn_cvt_pk_fp8_f32(vb.z, vb.w, p1, true);
            uint2 pk; pk.x = (uint32)p0; pk.y = (uint32)p1;
            ((uint2*)h8)[(size_t)(row0 + r) * 16 + g] = pk;
        }
    }
    // ---- logits: 64 rows x 8 heads = 512 tasks, 2 per thread ----
#pragma unroll
    for (int t = 0; t < 2; ++t) {
        int task = tid + t * 256;
        int r = task >> 3, hh = task & 7;
        if (row0 + r < N_NODES) {
            float as = 0.f, ad = 0.f;
#pragma unroll
            for (int c = 0; c < 16; ++c) {
                float v = hs[r * 132 + hh * 16 + c];
                as = fmaf(v, a_src[hh * 16 + c], as);
                ad = fmaf(v, a_dst[hh * 16 + c], ad);
            }
            ssrc[(row0 + r) * 8 + hh] = as;
            sdst[(row0 + r) * 8 + hh] = ad;
        }
    }
}

// block-local inclusive scan (256/block) + block sums
__global__ void scan1_kernel(const int* __restrict__ deg,
                             int* __restrict__ incl,
                             int* __restrict__ bsum)
{
    __shared__ int tmp[256];
    int i = blockIdx.x * 256 + threadIdx.x;
    int v = (i < N_NODES) ? deg[i] : 0;
    tmp[threadIdx.x] = v;
    __syncthreads();
    for (int o = 1; o < 256; o <<= 1) {
        int t = (threadIdx.x >= (unsigned)o) ? tmp[threadIdx.x - o] : 0;
        __syncthreads();
        tmp[threadIdx.x] += t;
        __syncthreads();
    }
    if (i < N_NODES) incl[i] = tmp[threadIdx.x];
    if (threadIdx.x == 255) bsum[blockIdx.x] = tmp[255];
}

// exclusive scan of block sums (nb <= 512), single block
__global__ void scan2_kernel(int* __restrict__ bsum, int nb)
{
    __shared__ int tmp[512];
    int v = (threadIdx.x < (unsigned)nb) ? bsum[threadIdx.x] : 0;
    tmp[threadIdx.x] = v;
    __syncthreads();
    for (int o = 1; o < 512; o <<= 1) {
        int t = (threadIdx.x >= (unsigned)o) ? tmp[threadIdx.x - o] : 0;
        __syncthreads();
        tmp[threadIdx.x] += t;
        __syncthreads();
    }
    if (threadIdx.x < (unsigned)nb) bsum[threadIdx.x] = tmp[threadIdx.x] - v;
}

// offsets[i+1] = incl[i] + bsum[block]; offsets[0] = 0
__global__ void scan3_kernel(const int* __restrict__ incl,
                             const int* __restrict__ bsum,
                             int* __restrict__ offsets)
{
    int i = blockIdx.x * 256 + threadIdx.x;
    if (i < N_NODES) offsets[i + 1] = incl[i] + bsum[blockIdx.x];
    if (i == 0) offsets[0] = 0;
}

// atomic-free scatter using precomputed rank
__global__ void scatter_kernel(const int* __restrict__ ei, int E,
                               const int* __restrict__ offsets,
                               const int* __restrict__ rank,
                               int* __restrict__ srcs)
{
    int e = blockIdx.x * blockDim.x + threadIdx.x;
    if (e >= E) return;
    int s = ei[e], d = ei[E + e];
    srcs[offsets[d] + rank[e]] = s;
}

// ---------------- layer 1 gather: one wave per dst node (fp8 h rows) --------
// LDS {s,w} staging: inner loop = 1 ds_read_b64 (loop-invariant addr + imm
// offset) instead of 2 ds_bpermute shuffles + index math.
__global__ void gather1_kernel(const uint32* __restrict__ h8,   // N x 32 dwords
                               const float* __restrict__ ssrc,
                               const float* __restrict__ sdst,
                               const int* __restrict__ offsets,
                               const int* __restrict__ srcs,
                               const float* __restrict__ b1,
                               float* __restrict__ out)
{
    __shared__ uint2 sw[4][64];
    int d = (blockIdx.x * blockDim.x + threadIdx.x) >> 6;
    int lane = threadIdx.x & 63;
    int wid = (threadIdx.x >> 6) & 3;
    if (d >= N_NODES) return;
    const int hw = lane & 7;            // head in weight phase
    const int half = lane >> 5;         // edge parity in accumulate phase
    const int u = lane & 31;            // dword in row: channels 4u..4u+3
    const int hc = u >> 2;              // head of my channels
    const float sd_w = sdst[d * H1 + hw];

    float acc0 = 0.f, acc1 = 0.f, acc2 = 0.f, acc3 = 0.f;
    float wsum = 0.f;

    // self-loop weight for my channel head
    float lgs = ssrc[d * H1 + hc] + sdst[d * H1 + hc];
    lgs = lgs >= 0.f ? lgs : NEG * lgs;
    const float ws_self = __expf(lgs);
    {   // only half 0 accumulates the self row (avoid double count)
        float m = (half == 0) ? ws_self : 0.f;
        uint32 p = h8[(size_t)d * 32 + u];
        v2f lo = __builtin_amdgcn_cvt_pk_f32_fp8((int)p, false);
        v2f hi = __builtin_amdgcn_cvt_pk_f32_fp8((int)p, true);
        acc0 = m * lo[0]; acc1 = m * lo[1];
        acc2 = m * hi[0]; acc3 = m * hi[1];
    }

    // (s,w) staging slot for my (half, head): read swp[16*t] = edge 2t+half
    const uint2* swp = &sw[wid][(half << 3) | hc];
    const int beg = offsets[d], end = offsets[d + 1];
    for (int base = beg; base < end; base += 8) {
        int cnt = end - base; if (cnt > 8) cnt = 8;
        int s_l = 0; float w_l = 0.f;
        if ((lane >> 3) < cnt) {
            s_l = srcs[base + (lane >> 3)];
            float lg = ssrc[s_l * H1 + hw] + sd_w;
            lg = lg >= 0.f ? lg : NEG * lg;
            w_l = __expf(lg);
        }
        wsum += w_l;
        sw[wid][lane] = make_uint2((uint32)s_l, __float_as_uint(w_l));
        asm volatile("s_waitcnt lgkmcnt(0)" ::: "memory");
#pragma unroll
        for (int t = 0; t < 4; ++t) {       // slots >= cnt carry w=0, s=0
            uint2 q = swp[16 * t];
            float w = __uint_as_float(q.y);
            uint32 p = h8[(size_t)q.x * 32 + u];
            v2f lo = __builtin_amdgcn_cvt_pk_f32_fp8((int)p, false);
            v2f hi = __builtin_amdgcn_cvt_pk_f32_fp8((int)p, true);
            acc0 = fmaf(w, lo[0], acc0);
            acc1 = fmaf(w, lo[1], acc1);
            acc2 = fmaf(w, hi[0], acc2);
            acc3 = fmaf(w, hi[1], acc3);
        }
    }
    // head-wise total: sum wsum over the 8 edge-slot groups (xor bits 3..5)
    wsum += __shfl_xor(wsum, 8);
    wsum += __shfl_xor(wsum, 16);
    wsum += __shfl_xor(wsum, 32);
    float ws = ws_self + __shfl(wsum, hc);
    // cross-half accumulator reduce
    acc0 += __shfl_xor(acc0, 32);
    acc1 += __shfl_xor(acc1, 32);
    acc2 += __shfl_xor(acc2, 32);
    acc3 += __shfl_xor(acc3, 32);
    if (half == 0) {
        float inv = 1.f / (ws + 1e-16f);
        float4 bb = ((const float4*)b1)[u];
        float4 r;
        r.x = fmaf(acc0, inv, bb.x); r.x = r.x > 0.f ? r.x : 0.f;
        r.y = fmaf(acc1, inv, bb.y); r.y = r.y > 0.f ? r.y : 0.f;
        r.z = fmaf(acc2, inv, bb.z); r.z = r.z > 0.f ? r.z : 0.f;
        r.w = fmaf(acc3, inv, bb.w); r.w = r.w > 0.f ? r.w : 0.f;
        ((float4*)(out + (size_t)d * D1))[u] = r;
    }
}

// ---------------- layer 2 GEMM + logits, fused ------------------------------
__global__ __launch_bounds__(256) void gemm2_kernel(
    const float* __restrict__ h, const float* __restrict__ W2,
    ushort16* __restrict__ h2b,
    const float* __restrict__ a_src, const float* __restrict__ a_dst,
    float* __restrict__ ssrc, float* __restrict__ sdst)
{
    __shared__ float w2s[40][132];
    __shared__ float hs[64][132];
    const int row0 = blockIdx.x * 64;
    const int tid = threadIdx.x;
#pragma unroll
    for (int i = 0; i < 20; ++i) {
        int idx = tid + i * 256;     // 0..5119
        int k = idx / 40, c = idx % 40;
        w2s[c][k] = W2[idx];
    }
#pragma unroll
    for (int i = 0; i < 8; ++i) {
        int idx = tid + i * 256;     // 0..2047
        int r = idx >> 5, c4 = idx & 31;
        float4 v = make_float4(0.f, 0.f, 0.f, 0.f);
        if (row0 + r < N_NODES)
            v = ((const float4*)h)[(size_t)(row0 + r) * 32 + c4];
        *(float4*)&hs[r][c4 * 4] = v;
    }
    __syncthreads();
    const int rr = tid >> 3;     // row pair (rr, rr+32)
    const int g  = tid & 7;      // cols 5g..5g+4
    float acc[2][5];
#pragma unroll
    for (int t = 0; t < 2; ++t)
#pragma unroll
        for (int j = 0; j < 5; ++j) acc[t][j] = 0.f;
    for (int k0 = 0; k0 < 128; k0 += 4) {
        float4 ha = *(const float4*)&hs[rr][k0];
        float4 hb = *(const float4*)&hs[rr + 32][k0];
#pragma unroll
        for (int j = 0; j < 5; ++j) {
            float4 wv = *(const float4*)&w2s[5 * g + j][k0];
            acc[0][j] = fmaf(ha.x, wv.x, acc[0][j]);
            acc[0][j] = fmaf(ha.y, wv.y, acc[0][j]);
            acc[0][j] = fmaf(ha.z, wv.z, acc[0][j]);
            acc[0][j] = fmaf(ha.w, wv.w, acc[0][j]);
            acc[1][j] = fmaf(hb.x, wv.x, acc[1][j]);
            acc[1][j] = fmaf(hb.y, wv.y, acc[1][j]);
            acc[1][j] = fmaf(hb.z, wv.z, acc[1][j]);
            acc[1][j] = fmaf(hb.w, wv.w, acc[1][j]);
        }
    }
#pragma unroll
    for (int t = 0; t < 2; ++t) {
        int row = row0 + rr + 32 * t;
        if (row < N_NODES) {
#pragma unroll
            for (int j = 0; j < 5; ++j)
                h2b[(size_t)row * 40 + 5 * g + j] = f2bf(acc[t][j]);
        }
    }
    __syncthreads();     // all reads of hs done
#pragma unroll
    for (int t = 0; t < 2; ++t)
#pragma unroll
        for (int j = 0; j < 5; ++j)
            hs[rr + 32 * t][5 * g + j] = acc[t][j];
    __syncthreads();
    if (tid < 64 && row0 + tid < N_NODES) {
        float as = 0.f, ad = 0.f;
#pragma unroll
        for (int c = 0; c < 40; ++c) {
            float v = hs[tid][c];
            as = fmaf(v, a_src[c], as);
            ad = fmaf(v, a_dst[c], ad);
        }
        ssrc[row0 + tid] = as;
        sdst[row0 + tid] = ad;
    }
}

// ---------------- layer 2 gather + log_softmax: one wave per node (bf16) ----
// LDS {s,w} staging (1 ds_read_b64 vs 2 bpermutes), LDS cross-group reduce,
// 16-lane softmax butterflies.
__global__ void gather2_kernel(const uint32* __restrict__ h2b,  // N x 20 uints
                               const float* __restrict__ ssrc,
                               const float* __restrict__ sdst,
                               const int* __restrict__ offsets,
                               const int* __restrict__ srcs,
                               const float* __restrict__ b2,
                               float* __restrict__ out)
{
    __shared__ uint2 sw[4][64];
    __shared__ __align__(16) float4 pacc[4][64];
    int d = (blockIdx.x * blockDim.x + threadIdx.x) >> 6;
    int lane = threadIdx.x & 63;
    int wid = (threadIdx.x >> 6) & 3;
    if (d >= N_NODES) return;
    const float sd = sdst[d];
    const int g = lane / 10;              // group 0..6 (g<6 accumulate)
    const int c = lane - 10 * g;          // uint2 within row: channels 4c..4c+3
    const bool act = lane < 10;           // lanes that own the output
    const uint2* h2v = (const uint2*)h2b; // rows of 10 uint2
    float acc0 = 0.f, acc1 = 0.f, acc2 = 0.f, acc3 = 0.f, wl = 0.f;

    // self-loop (output lanes only)
    float ws_self;
    {
        float lg = ssrc[d] + sd; lg = lg >= 0.f ? lg : NEG * lg;
        ws_self = __expf(lg);
        if (act) {
            uint2 p = h2v[(size_t)d * 10 + lane];
            acc0 = ws_self * bf_lo(p.x); acc1 = ws_self * bf_hi(p.x);
            acc2 = ws_self * bf_lo(p.y); acc3 = ws_self * bf_hi(p.y);
        }
    }
    const int beg = offsets[d], end = offsets[d + 1];
    for (int base = beg; base < end; base += 64) {
        int cnt = end - base; if (cnt > 64) cnt = 64;
        int s_l = 0; float w_l = 0.f;
        if (lane < cnt) {
            s_l = srcs[base + lane];
            float lg = ssrc[s_l] + sd; lg = lg >= 0.f ? lg : NEG * lg;
            w_l = __expf(lg);
        }
        wl += w_l;
        sw[wid][lane] = make_uint2((uint32)s_l, __float_as_uint(w_l));
        asm volatile("s_waitcnt lgkmcnt(0)" ::: "memory");
        for (int j = 0; j < cnt; j += 6) {
            int jj = j + g;
            uint2 q = sw[wid][jj & 63];
            float w = ((g < 6) & (jj < cnt)) ? __uint_as_float(q.y) : 0.f;
            uint2 p = h2v[(size_t)q.x * 10 + c];
            acc0 = fmaf(w, bf_lo(p.x), acc0);
            acc1 = fmaf(w, bf_hi(p.x), acc1);
            acc2 = fmaf(w, bf_lo(p.y), acc2);
            acc3 = fmaf(w, bf_hi(p.y), acc3);
        }
    }
    // denominator: one full-wave reduce at the end
    float t = wl;
#pragma unroll
    for (int o = 32; o > 0; o >>= 1) t += __shfl_xor(t, o);
    float ws = ws_self + t;
    // cross-group accumulator reduce via LDS (partials at lanes c + 10k)
    float4 mine; mine.x = acc0; mine.y = acc1; mine.z = acc2; mine.w = acc3;
    pacc[wid][lane] = mine;
    asm volatile("s_waitcnt lgkmcnt(0)" ::: "memory");
    float l0 = -INFINITY, l1 = -INFINITY, l2 = -INFINITY, l3 = -INFINITY;
    if (act) {
        float4 s0 = pacc[wid][lane];
        float4 s1 = pacc[wid][lane + 10];
        float4 s2 = pacc[wid][lane + 20];
        float4 s3 = pacc[wid][lane + 30];
        float4 s4 = pacc[wid][lane + 40];
        float4 s5 = pacc[wid][lane + 50];
        float a0 = s0.x + s1.x + s2.x + s3.x + s4.x + s5.x;
        float a1 = s0.y + s1.y + s2.y + s3.y + s4.y + s5.y;
        float a2 = s0.z + s1.z + s2.z + s3.z + s4.z + s5.z;
        float a3 = s0.w + s1.w + s2.w + s3.w + s4.w + s5.w;
        float inv = 1.f / (ws + 1e-16f);
        l0 = fmaf(a0, inv, b2[4 * lane + 0]);
        l1 = fmaf(a1, inv, b2[4 * lane + 1]);
        l2 = fmaf(a2, inv, b2[4 * lane + 2]);
        l3 = fmaf(a3, inv, b2[4 * lane + 3]);
    }
    // softmax over 10 active lanes: 16-lane butterflies suffice
    float m = fmaxf(fmaxf(l0, l1), fmaxf(l2, l3));
#pragma unroll
    for (int o = 8; o > 0; o >>= 1) m = fmaxf(m, __shfl_xor(m, o));
    float ex = act ? (__expf(l0 - m) + __expf(l1 - m) + __expf(l2 - m) + __expf(l3 - m)) : 0.f;
#pragma unroll
    for (int o = 8; o > 0; o >>= 1) ex += __shfl_xor(ex, o);
    float lse = __logf(ex) + m;
    if (act) {
        float4 r;
        r.x = l0 - lse; r.y = l1 - lse; r.z = l2 - lse; r.w = l3 - lse;
        ((float4*)(out + (size_t)d * NCLS))[lane] = r;
    }
}

extern "C" void kernel_launch(void* const* d_in, const int* in_sizes, int n_in,
                              void* d_out, int out_size, void* d_ws, size_t ws_size,
                              hipStream_t stream)
{
    const float* x   = (const float*)d_in[0];
    const int*   ei  = (const int*)  d_in[1];
    const float* W1  = (const float*)d_in[2];
    const float* as1 = (const float*)d_in[3];
    const float* ad1 = (const float*)d_in[4];
    const float* b1  = (const float*)d_in[5];
    const float* W2  = (const float*)d_in[6];
    const float* as2 = (const float*)d_in[7];
    const float* ad2 = (const float*)d_in[8];
    const float* b2  = (const float*)d_in[9];
    float* out = (float*)d_out;
    const int E = in_sizes[1] / 2;

    float* ws = (float*)d_ws;
    size_t off = 0;
    uint32* h1f8 = (uint32*)(ws + off); off += (size_t)N_NODES * 32;  // fp8 N x 128
    float* h1r  = ws + off; off += (size_t)N_NODES * D1;
    float* ss1  = ws + off; off += (size_t)N_NODES * H1;
    float* sd1  = ws + off; off += (size_t)N_NODES * H1;
    uint32* h2b = (uint32*)(ws + off); off += (size_t)N_NODES * 20;   // bf16 N x 40
    float* ss2  = ws + off; off += N_NODES;
    float* sd2  = ws + off; off += N_NODES;
    unsigned short* w1t = (unsigned short*)(ws + off); off += 8704;   // bf16 W1^T [128][136]
    int* ib = (int*)(ws + off);
    size_t ioff = 0;
    int* deg     = ib + ioff; ioff += N_NODES;      // zeroed in prep_w1_kernel
    int* incl    = ib + ioff; ioff += N_NODES;
    int* offsets = ib + ioff; ioff += N_NODES + 1;
    int* bsum    = ib + ioff; ioff += 512;
    int* rank    = ib + ioff; ioff += E;
    int* srcs    = ib + ioff; ioff += E;

    const int nb = (N_NODES + 255) / 256;           // 391

    // W1 -> bf16 transposed+padded + deg zeroing (replaces memset dispatch)
    prep_w1_kernel<<<nb, 256, 0, stream>>>(W1, w1t, deg);

    // fused layer-1 MFMA gemm(+logits) + CSR count (period-3 interleave,
    // 8 edges/thread in count blocks)
    gemm1_count_kernel<<<NG + NCB, 256, 0, stream>>>(x, w1t, h1f8, as1, ad1,
                                                     ss1, sd1, ei, E, deg, rank);
    // CSR finish
    scan1_kernel<<<nb, 256, 0, stream>>>(deg, incl, bsum);
    scan2_kernel<<<1, 512, 0, stream>>>(bsum, nb);
    scan3_kernel<<<nb, 256, 0, stream>>>(incl, bsum, offsets);
    scatter_kernel<<<(E + 255) / 256, 256, 0, stream>>>(ei, E, offsets, rank, srcs);

    // layer 1 gather
    gather1_kernel<<<(N_NODES * 64 + 255) / 256, 256, 0, stream>>>(h1f8, ss1, sd1, offsets, srcs, b1, h1r);

    // layer 2 (gemm + logits fused)
    gemm2_kernel<<<(N_NODES + 63) / 64, 256, 0, stream>>>(h1r, W2, (ushort16*)h2b, as2, ad2, ss2, sd2);
    gather2_kernel<<<(N_NODES * 64 + 255) / 256, 256, 0, stream>>>(h2b, ss2, sd2, offsets, srcs, b2, out);
}

// Round 6
// 367.185 us; speedup vs baseline: 1.0146x; 1.0146x over previous
//
#include <hip/hip_runtime.h>
#include <math.h>

#define N_NODES 100000
#define F_IN    128
#define H1      8
#define C1      16
#define D1      128   // H1*C1
#define NCLS    40
#define NEG     0.2f

typedef unsigned int uint32;
typedef unsigned short ushort16;
typedef float v2f __attribute__((ext_vector_type(2)));
typedef __attribute__((ext_vector_type(8))) short bf16x8;   // 4 VGPRs, MFMA A/B frag
typedef __attribute__((ext_vector_type(4))) float f32x4;    // MFMA C/D frag

__device__ __forceinline__ ushort16 f2bf(float f) {
    unsigned int u = __float_as_uint(f);
    u += 0x7fffu + ((u >> 16) & 1u);          // round-to-nearest-even
    return (ushort16)(u >> 16);
}
__device__ __forceinline__ float bf_lo(uint32 p) { return __uint_as_float(p << 16); }
__device__ __forceinline__ float bf_hi(uint32 p) { return __uint_as_float(p & 0xffff0000u); }

#define NG 1563   // gemm blocks (64 rows each)

// W1 -> bf16 transposed+padded [128][136]; also zeroes deg (replaces memset).
__global__ void prep_w1_kernel(const float* __restrict__ W,
                               unsigned short* __restrict__ w1t,
                               int* __restrict__ deg)
{
    int idx = blockIdx.x * 256 + threadIdx.x;
    if (idx < 16384) {
        int n = idx & 127, k = idx >> 7;        // coalesced read of W[k][n]
        w1t[n * 136 + k] = f2bf(W[k * 128 + n]);
    }
    if (idx < N_NODES) deg[idx] = 0;
}

// ---------------- fused: layer-1 MFMA GEMM(+logits) blocks + CSR-count ------
// Proven round-1/4 interleave (1:4, 1 edge/thread): atomic-throughput-bound
// count blocks co-resident with LDS/MFMA-bound gemm blocks from t=0.
__global__ __launch_bounds__(256) void gemm1_count_kernel(
    const float* __restrict__ x, const unsigned short* __restrict__ w1t,
    uint32* __restrict__ h8,            // fp8 rows, N x 32 dwords
    const float* __restrict__ a_src, const float* __restrict__ a_dst,
    float* __restrict__ ssrc, float* __restrict__ sdst,
    const int* __restrict__ ei, int E,
    int* __restrict__ deg, int* __restrict__ rank)
{
    // 34816 B: holds W1^T bf16 [128][136] during MFMA, then hs fp32 [64][132]
    __shared__ __align__(16) uint32 wbuf[8704];
    const int bid = blockIdx.x;
    const int tid = threadIdx.x;
    const bool is_gemm = ((bid % 5) == 0) && (bid / 5 < NG);
    if (!is_gemm) {
        // ---------------- count path: rank[e] = old deg[dst]++ --------------
        int ng_before = bid / 5 + ((bid % 5) ? 1 : 0);   // gemm blocks < bid
        if (ng_before > NG) ng_before = NG;
        int c = bid - ng_before;
        long long e = (long long)c * 256 + tid;
        if (e < E) rank[e] = atomicAdd(&deg[ei[E + e]], 1);
        return;
    }
    const int row0 = (bid / 5) * 64;
    const int wid = tid >> 6, lane = tid & 63;

    // ---- A fragments straight from global: wave w owns rows 16w..16w+15.
    const int arow = row0 + wid * 16 + (lane & 15);
    const bool rowok = arow < N_NODES;
    const float* xp = x + (size_t)arow * 128 + 8 * (lane >> 4);
    float4 af0[4], af1[4];
#pragma unroll
    for (int s = 0; s < 4; ++s) {
        if (rowok) {
            af0[s] = *(const float4*)(xp + 32 * s);
            af1[s] = *(const float4*)(xp + 32 * s + 4);
        } else {
            af0[s] = make_float4(0.f, 0.f, 0.f, 0.f);
            af1[s] = make_float4(0.f, 0.f, 0.f, 0.f);
        }
    }
    // ---- stage W1^T bf16 into LDS (linear 34816 B copy, pad included) ----
    {
        const uint32* g = (const uint32*)w1t;
#pragma unroll
        for (int i = 0; i < 8; ++i)
            ((uint4*)wbuf)[tid + i * 256] = ((const uint4*)g)[tid + i * 256];
        wbuf[8192 + tid] = g[8192 + tid];
        wbuf[8448 + tid] = g[8448 + tid];
    }
    // ---- convert A to bf16 fragments (same k-order as B reads: 8g+j) ----
    bf16x8 a[4];
#pragma unroll
    for (int s = 0; s < 4; ++s) {
        a[s][0] = (short)f2bf(af0[s].x); a[s][1] = (short)f2bf(af0[s].y);
        a[s][2] = (short)f2bf(af0[s].z); a[s][3] = (short)f2bf(af0[s].w);
        a[s][4] = (short)f2bf(af1[s].x); a[s][5] = (short)f2bf(af1[s].y);
        a[s][6] = (short)f2bf(af1[s].z); a[s][7] = (short)f2bf(af1[s].w);
    }
    __syncthreads();
    // ---- K loop: 4 steps x 8 col-fragments = 32 MFMAs / wave ----
    f32x4 acc[8];
#pragma unroll
    for (int j = 0; j < 8; ++j)
#pragma unroll
        for (int r = 0; r < 4; ++r) acc[j][r] = 0.f;
    const unsigned short* wb = (const unsigned short*)wbuf;
    const int bc = lane & 15, ko = 8 * (lane >> 4);
#pragma unroll
    for (int s = 0; s < 4; ++s) {
#pragma unroll
        for (int j = 0; j < 8; ++j) {
            bf16x8 b = *(const bf16x8*)&wb[(16 * j + bc) * 136 + 32 * s + ko];
            acc[j] = __builtin_amdgcn_mfma_f32_16x16x32_bf16(a[s], b, acc[j], 0, 0, 0);
        }
    }
    __syncthreads();   // all MFMA operand reads of wbuf done
    // ---- write acc to hs[64][132] (C/D map: col=lane&15, row=(lane>>4)*4+r)
    float* hs = (float*)wbuf;
    const int cr0 = wid * 16 + 4 * (lane >> 4);
#pragma unroll
    for (int j = 0; j < 8; ++j)
#pragma unroll
        for (int r = 0; r < 4; ++r)
            hs[(cr0 + r) * 132 + 16 * j + bc] = acc[j][r];
    __syncthreads();
    // ---- fp8 pack: 64 rows x 16 uint2-groups, 4 tasks/thread ----
#pragma unroll
    for (int t = 0; t < 4; ++t) {
        int task = tid + t * 256;     // 0..1023
        int r = task >> 4, g = task & 15;
        if (row0 + r < N_NODES) {
            float4 va = *(const float4*)&hs[r * 132 + 8 * g];
            float4 vb = *(const float4*)&hs[r * 132 + 8 * g + 4];
            int p0 = __builtin_amdgcn_cvt_pk_fp8_f32(va.x, va.y, 0, false);
            p0     = __builtin_amdgcn_cvt_pk_fp8_f32(va.z, va.w, p0, true);
            int p1 = __builtin_amdgcn_cvt_pk_fp8_f32(vb.x, vb.y, 0, false);
            p1     = __builtin_amdgcn_cvt_pk_fp8_f32(vb.z, vb.w, p1, true);
            uint2 pk; pk.x = (uint32)p0; pk.y = (uint32)p1;
            ((uint2*)h8)[(size_t)(row0 + r) * 16 + g] = pk;
        }
    }
    // ---- logits: 64 rows x 8 heads = 512 tasks, 2 per thread ----
#pragma unroll
    for (int t = 0; t < 2; ++t) {
        int task = tid + t * 256;
        int r = task >> 3, hh = task & 7;
        if (row0 + r < N_NODES) {
            float as = 0.f, ad = 0.f;
#pragma unroll
            for (int c = 0; c < 16; ++c) {
                float v = hs[r * 132 + hh * 16 + c];
                as = fmaf(v, a_src[hh * 16 + c], as);
                ad = fmaf(v, a_dst[hh * 16 + c], ad);
            }
            ssrc[(row0 + r) * 8 + hh] = as;
            sdst[(row0 + r) * 8 + hh] = ad;
        }
    }
}

// block-local inclusive scan (256/block) + raw block sums
__global__ void scan1_kernel(const int* __restrict__ deg,
                             int* __restrict__ incl,
                             int* __restrict__ bsum)
{
    __shared__ int tmp[256];
    int i = blockIdx.x * 256 + threadIdx.x;
    int v = (i < N_NODES) ? deg[i] : 0;
    tmp[threadIdx.x] = v;
    __syncthreads();
    for (int o = 1; o < 256; o <<= 1) {
        int t = (threadIdx.x >= (unsigned)o) ? tmp[threadIdx.x - o] : 0;
        __syncthreads();
        tmp[threadIdx.x] += t;
        __syncthreads();
    }
    if (i < N_NODES) incl[i] = tmp[threadIdx.x];
    if (threadIdx.x == 255) bsum[blockIdx.x] = tmp[255];
}

// offsets[i+1] = incl[i] + prefix(bsum, block); each block sums its own
// prefix of the raw block sums (<=2 loads/thread) — replaces scan2+scan3.
__global__ void scan3_kernel(const int* __restrict__ incl,
                             const int* __restrict__ bsum,
                             int* __restrict__ offsets)
{
    __shared__ int red[4];
    int pre = 0;
    for (int i = threadIdx.x; i < blockIdx.x; i += 256) pre += bsum[i];
#pragma unroll
    for (int o = 32; o > 0; o >>= 1) pre += __shfl_xor(pre, o);
    if ((threadIdx.x & 63) == 0) red[threadIdx.x >> 6] = pre;
    __syncthreads();
    int total = red[0] + red[1] + red[2] + red[3];
    int i = blockIdx.x * 256 + threadIdx.x;
    if (i < N_NODES) offsets[i + 1] = incl[i] + total;
    if (i == 0) offsets[0] = 0;
}

// atomic-free scatter using precomputed rank
__global__ void scatter_kernel(const int* __restrict__ ei, int E,
                               const int* __restrict__ offsets,
                               const int* __restrict__ rank,
                               int* __restrict__ srcs)
{
    int e = blockIdx.x * blockDim.x + threadIdx.x;
    if (e >= E) return;
    int s = ei[e], d = ei[E + e];
    srcs[offsets[d] + rank[e]] = s;
}

// ---------------- layer 1 gather: one wave per dst node (fp8 h rows) --------
// LDS {s,w} staging + srcs prefetch pipeline: next chunk's srcs load issued
// before processing the current chunk (hides ~200cyc L2 latency).
__global__ void gather1_kernel(const uint32* __restrict__ h8,   // N x 32 dwords
                               const float* __restrict__ ssrc,
                               const float* __restrict__ sdst,
                               const int* __restrict__ offsets,
                               const int* __restrict__ srcs,
                               const float* __restrict__ b1,
                               float* __restrict__ out)
{
    __shared__ uint2 sw[4][64];
    int d = (blockIdx.x * blockDim.x + threadIdx.x) >> 6;
    int lane = threadIdx.x & 63;
    int wid = (threadIdx.x >> 6) & 3;
    if (d >= N_NODES) return;
    const int hw = lane & 7;            // head in weight phase
    const int half = lane >> 5;         // edge parity in accumulate phase
    const int u = lane & 31;            // dword in row: channels 4u..4u+3
    const int hc = u >> 2;              // head of my channels
    const float sd_w = sdst[d * H1 + hw];

    float acc0 = 0.f, acc1 = 0.f, acc2 = 0.f, acc3 = 0.f;
    float wsum = 0.f;

    // self-loop weight for my channel head
    float lgs = ssrc[d * H1 + hc] + sdst[d * H1 + hc];
    lgs = lgs >= 0.f ? lgs : NEG * lgs;
    const float ws_self = __expf(lgs);
    {   // only half 0 accumulates the self row (avoid double count)
        float m = (half == 0) ? ws_self : 0.f;
        uint32 p = h8[(size_t)d * 32 + u];
        v2f lo = __builtin_amdgcn_cvt_pk_f32_fp8((int)p, false);
        v2f hi = __builtin_amdgcn_cvt_pk_f32_fp8((int)p, true);
        acc0 = m * lo[0]; acc1 = m * lo[1];
        acc2 = m * hi[0]; acc3 = m * hi[1];
    }

    // (s,w) staging slot for my (half, head): read swp[16*t] = edge 2t+half
    const uint2* swp = &sw[wid][(half << 3) | hc];
    const int beg = offsets[d], end = offsets[d + 1];
    int sl_next = 0;
    {
        int c0 = end - beg; if (c0 > 8) c0 = 8;
        if ((lane >> 3) < c0) sl_next = srcs[beg + (lane >> 3)];
    }
    for (int base = beg; base < end; base += 8) {
        int cnt = end - base; if (cnt > 8) cnt = 8;
        int s_l = sl_next;                 // stale beyond cnt: w=0, index valid
        float w_l = 0.f;
        if ((lane >> 3) < cnt) {
            float lg = ssrc[s_l * H1 + hw] + sd_w;
            lg = lg >= 0.f ? lg : NEG * lg;
            w_l = __expf(lg);
        }
        {   // prefetch next chunk's srcs under current processing
            int nb2 = base + 8;
            int cn = end - nb2; if (cn > 8) cn = 8;
            if ((lane >> 3) < cn) sl_next = srcs[nb2 + (lane >> 3)];
        }
        wsum += w_l;
        sw[wid][lane] = make_uint2((uint32)s_l, __float_as_uint(w_l));
        asm volatile("s_waitcnt lgkmcnt(0)" ::: "memory");
#pragma unroll
        for (int t = 0; t < 4; ++t) {       // slots >= cnt carry w=0
            uint2 q = swp[16 * t];
            float w = __uint_as_float(q.y);
            uint32 p = h8[(size_t)q.x * 32 + u];
            v2f lo = __builtin_amdgcn_cvt_pk_f32_fp8((int)p, false);
            v2f hi = __builtin_amdgcn_cvt_pk_f32_fp8((int)p, true);
            acc0 = fmaf(w, lo[0], acc0);
            acc1 = fmaf(w, lo[1], acc1);
            acc2 = fmaf(w, hi[0], acc2);
            acc3 = fmaf(w, hi[1], acc3);
        }
    }
    // head-wise total: sum wsum over the 8 edge-slot groups (xor bits 3..5)
    wsum += __shfl_xor(wsum, 8);
    wsum += __shfl_xor(wsum, 16);
    wsum += __shfl_xor(wsum, 32);
    float ws = ws_self + __shfl(wsum, hc);
    // cross-half accumulator reduce
    acc0 += __shfl_xor(acc0, 32);
    acc1 += __shfl_xor(acc1, 32);
    acc2 += __shfl_xor(acc2, 32);
    acc3 += __shfl_xor(acc3, 32);
    if (half == 0) {
        float inv = 1.f / (ws + 1e-16f);
        float4 bb = ((const float4*)b1)[u];
        float4 r;
        r.x = fmaf(acc0, inv, bb.x); r.x = r.x > 0.f ? r.x : 0.f;
        r.y = fmaf(acc1, inv, bb.y); r.y = r.y > 0.f ? r.y : 0.f;
        r.z = fmaf(acc2, inv, bb.z); r.z = r.z > 0.f ? r.z : 0.f;
        r.w = fmaf(acc3, inv, bb.w); r.w = r.w > 0.f ? r.w : 0.f;
        ((float4*)(out + (size_t)d * D1))[u] = r;
    }
}

// ---------------- layer 2 GEMM + logits, fused ------------------------------
__global__ __launch_bounds__(256) void gemm2_kernel(
    const float* __restrict__ h, const float* __restrict__ W2,
    ushort16* __restrict__ h2b,
    const float* __restrict__ a_src, const float* __restrict__ a_dst,
    float* __restrict__ ssrc, float* __restrict__ sdst)
{
    __shared__ float w2s[40][132];
    __shared__ float hs[64][132];
    const int row0 = blockIdx.x * 64;
    const int tid = threadIdx.x;
#pragma unroll
    for (int i = 0; i < 20; ++i) {
        int idx = tid + i * 256;     // 0..5119
        int k = idx / 40, c = idx % 40;
        w2s[c][k] = W2[idx];
    }
#pragma unroll
    for (int i = 0; i < 8; ++i) {
        int idx = tid + i * 256;     // 0..2047
        int r = idx >> 5, c4 = idx & 31;
        float4 v = make_float4(0.f, 0.f, 0.f, 0.f);
        if (row0 + r < N_NODES)
            v = ((const float4*)h)[(size_t)(row0 + r) * 32 + c4];
        *(float4*)&hs[r][c4 * 4] = v;
    }
    __syncthreads();
    const int rr = tid >> 3;     // row pair (rr, rr+32)
    const int g  = tid & 7;      // cols 5g..5g+4
    float acc[2][5];
#pragma unroll
    for (int t = 0; t < 2; ++t)
#pragma unroll
        for (int j = 0; j < 5; ++j) acc[t][j] = 0.f;
    for (int k0 = 0; k0 < 128; k0 += 4) {
        float4 ha = *(const float4*)&hs[rr][k0];
        float4 hb = *(const float4*)&hs[rr + 32][k0];
#pragma unroll
        for (int j = 0; j < 5; ++j) {
            float4 wv = *(const float4*)&w2s[5 * g + j][k0];
            acc[0][j] = fmaf(ha.x, wv.x, acc[0][j]);
            acc[0][j] = fmaf(ha.y, wv.y, acc[0][j]);
            acc[0][j] = fmaf(ha.z, wv.z, acc[0][j]);
            acc[0][j] = fmaf(ha.w, wv.w, acc[0][j]);
            acc[1][j] = fmaf(hb.x, wv.x, acc[1][j]);
            acc[1][j] = fmaf(hb.y, wv.y, acc[1][j]);
            acc[1][j] = fmaf(hb.z, wv.z, acc[1][j]);
            acc[1][j] = fmaf(hb.w, wv.w, acc[1][j]);
        }
    }
#pragma unroll
    for (int t = 0; t < 2; ++t) {
        int row = row0 + rr + 32 * t;
        if (row < N_NODES) {
#pragma unroll
            for (int j = 0; j < 5; ++j)
                h2b[(size_t)row * 40 + 5 * g + j] = f2bf(acc[t][j]);
        }
    }
    __syncthreads();     // all reads of hs done
#pragma unroll
    for (int t = 0; t < 2; ++t)
#pragma unroll
        for (int j = 0; j < 5; ++j)
            hs[rr + 32 * t][5 * g + j] = acc[t][j];
    __syncthreads();
    if (tid < 64 && row0 + tid < N_NODES) {
        float as = 0.f, ad = 0.f;
#pragma unroll
        for (int c = 0; c < 40; ++c) {
            float v = hs[tid][c];
            as = fmaf(v, a_src[c], as);
            ad = fmaf(v, a_dst[c], ad);
        }
        ssrc[row0 + tid] = as;
        sdst[row0 + tid] = ad;
    }
}

// ---------------- layer 2 gather + log_softmax: one wave per node (bf16) ----
// LDS {s,w} staging + srcs prefetch pipeline + LDS cross-group reduce.
__global__ void gather2_kernel(const uint32* __restrict__ h2b,  // N x 20 uints
                               const float* __restrict__ ssrc,
                               const float* __restrict__ sdst,
                               const int* __restrict__ offsets,
                               const int* __restrict__ srcs,
                               const float* __restrict__ b2,
                               float* __restrict__ out)
{
    __shared__ uint2 sw[4][64];
    __shared__ __align__(16) float4 pacc[4][64];
    int d = (blockIdx.x * blockDim.x + threadIdx.x) >> 6;
    int lane = threadIdx.x & 63;
    int wid = (threadIdx.x >> 6) & 3;
    if (d >= N_NODES) return;
    const float sd = sdst[d];
    const int g = lane / 10;              // group 0..6 (g<6 accumulate)
    const int c = lane - 10 * g;          // uint2 within row: channels 4c..4c+3
    const bool act = lane < 10;           // lanes that own the output
    const uint2* h2v = (const uint2*)h2b; // rows of 10 uint2
    float acc0 = 0.f, acc1 = 0.f, acc2 = 0.f, acc3 = 0.f, wl = 0.f;

    // self-loop (output lanes only)
    float ws_self;
    {
        float lg = ssrc[d] + sd; lg = lg >= 0.f ? lg : NEG * lg;
        ws_self = __expf(lg);
        if (act) {
            uint2 p = h2v[(size_t)d * 10 + lane];
            acc0 = ws_self * bf_lo(p.x); acc1 = ws_self * bf_hi(p.x);
            acc2 = ws_self * bf_lo(p.y); acc3 = ws_self * bf_hi(p.y);
        }
    }
    const int beg = offsets[d], end = offsets[d + 1];
    int sl_next = 0;
    {
        int c0 = end - beg; if (c0 > 64) c0 = 64;
        if (lane < c0) sl_next = srcs[beg + lane];
    }
    for (int base = beg; base < end; base += 64) {
        int cnt = end - base; if (cnt > 64) cnt = 64;
        int s_l = sl_next;                 // stale beyond cnt: w=0, index valid
        float w_l = 0.f;
        if (lane < cnt) {
            float lg = ssrc[s_l] + sd; lg = lg >= 0.f ? lg : NEG * lg;
            w_l = __expf(lg);
        }
        {   // prefetch next chunk's srcs under current processing
            int nb2 = base + 64;
            int cn = end - nb2; if (cn > 64) cn = 64;
            if (lane < cn) sl_next = srcs[nb2 + lane];
        }
        wl += w_l;
        sw[wid][lane] = make_uint2((uint32)s_l, __float_as_uint(w_l));
        asm volatile("s_waitcnt lgkmcnt(0)" ::: "memory");
        for (int j = 0; j < cnt; j += 6) {
            int jj = j + g;
            uint2 q = sw[wid][jj & 63];
            float w = ((g < 6) & (jj < cnt)) ? __uint_as_float(q.y) : 0.f;
            uint2 p = h2v[(size_t)q.x * 10 + c];
            acc0 = fmaf(w, bf_lo(p.x), acc0);
            acc1 = fmaf(w, bf_hi(p.x), acc1);
            acc2 = fmaf(w, bf_lo(p.y), acc2);
            acc3 = fmaf(w, bf_hi(p.y), acc3);
        }
    }
    // denominator: one full-wave reduce at the end
    float t = wl;
#pragma unroll
    for (int o = 32; o > 0; o >>= 1) t += __shfl_xor(t, o);
    float ws = ws_self + t;
    // cross-group accumulator reduce via LDS (partials at lanes c + 10k)
    float4 mine; mine.x = acc0; mine.y = acc1; mine.z = acc2; mine.w = acc3;
    pacc[wid][lane] = mine;
    asm volatile("s_waitcnt lgkmcnt(0)" ::: "memory");
    float l0 = -INFINITY, l1 = -INFINITY, l2 = -INFINITY, l3 = -INFINITY;
    if (act) {
        float4 s0 = pacc[wid][lane];
        float4 s1 = pacc[wid][lane + 10];
        float4 s2 = pacc[wid][lane + 20];
        float4 s3 = pacc[wid][lane + 30];
        float4 s4 = pacc[wid][lane + 40];
        float4 s5 = pacc[wid][lane + 50];
        float a0 = s0.x + s1.x + s2.x + s3.x + s4.x + s5.x;
        float a1 = s0.y + s1.y + s2.y + s3.y + s4.y + s5.y;
        float a2 = s0.z + s1.z + s2.z + s3.z + s4.z + s5.z;
        float a3 = s0.w + s1.w + s2.w + s3.w + s4.w + s5.w;
        float inv = 1.f / (ws + 1e-16f);
        l0 = fmaf(a0, inv, b2[4 * lane + 0]);
        l1 = fmaf(a1, inv, b2[4 * lane + 1]);
        l2 = fmaf(a2, inv, b2[4 * lane + 2]);
        l3 = fmaf(a3, inv, b2[4 * lane + 3]);
    }
    // softmax over 10 active lanes: 16-lane butterflies suffice
    float m = fmaxf(fmaxf(l0, l1), fmaxf(l2, l3));
#pragma unroll
    for (int o = 8; o > 0; o >>= 1) m = fmaxf(m, __shfl_xor(m, o));
    float ex = act ? (__expf(l0 - m) + __expf(l1 - m) + __expf(l2 - m) + __expf(l3 - m)) : 0.f;
#pragma unroll
    for (int o = 8; o > 0; o >>= 1) ex += __shfl_xor(ex, o);
    float lse = __logf(ex) + m;
    if (act) {
        float4 r;
        r.x = l0 - lse; r.y = l1 - lse; r.z = l2 - lse; r.w = l3 - lse;
        ((float4*)(out + (size_t)d * NCLS))[lane] = r;
    }
}

extern "C" void kernel_launch(void* const* d_in, const int* in_sizes, int n_in,
                              void* d_out, int out_size, void* d_ws, size_t ws_size,
                              hipStream_t stream)
{
    const float* x   = (const float*)d_in[0];
    const int*   ei  = (const int*)  d_in[1];
    const float* W1  = (const float*)d_in[2];
    const float* as1 = (const float*)d_in[3];
    const float* ad1 = (const float*)d_in[4];
    const float* b1  = (const float*)d_in[5];
    const float* W2  = (const float*)d_in[6];
    const float* as2 = (const float*)d_in[7];
    const float* ad2 = (const float*)d_in[8];
    const float* b2  = (const float*)d_in[9];
    float* out = (float*)d_out;
    const int E = in_sizes[1] / 2;

    float* ws = (float*)d_ws;
    size_t off = 0;
    uint32* h1f8 = (uint32*)(ws + off); off += (size_t)N_NODES * 32;  // fp8 N x 128
    float* h1r  = ws + off; off += (size_t)N_NODES * D1;
    float* ss1  = ws + off; off += (size_t)N_NODES * H1;
    float* sd1  = ws + off; off += (size_t)N_NODES * H1;
    uint32* h2b = (uint32*)(ws + off); off += (size_t)N_NODES * 20;   // bf16 N x 40
    float* ss2  = ws + off; off += N_NODES;
    float* sd2  = ws + off; off += N_NODES;
    unsigned short* w1t = (unsigned short*)(ws + off); off += 8704;   // bf16 W1^T [128][136]
    int* ib = (int*)(ws + off);
    size_t ioff = 0;
    int* deg     = ib + ioff; ioff += N_NODES;      // zeroed in prep_w1_kernel
    int* incl    = ib + ioff; ioff += N_NODES;
    int* offsets = ib + ioff; ioff += N_NODES + 1;
    int* bsum    = ib + ioff; ioff += 512;
    int* rank    = ib + ioff; ioff += E;
    int* srcs    = ib + ioff; ioff += E;

    const int nb = (N_NODES + 255) / 256;           // 391
    const int nc = (E + 255) / 256;                 // count blocks (6250)

    // W1 -> bf16 transposed+padded + deg zeroing (replaces memset dispatch)
    prep_w1_kernel<<<nb, 256, 0, stream>>>(W1, w1t, deg);

    // fused layer-1 MFMA gemm(+logits) + CSR count (proven 1:4 interleave)
    gemm1_count_kernel<<<NG + nc, 256, 0, stream>>>(x, w1t, h1f8, as1, ad1,
                                                    ss1, sd1, ei, E, deg, rank);
    // CSR finish (scan2 folded into scan3)
    scan1_kernel<<<nb, 256, 0, stream>>>(deg, incl, bsum);
    scan3_kernel<<<nb, 256, 0, stream>>>(incl, bsum, offsets);
    scatter_kernel<<<(E + 255) / 256, 256, 0, stream>>>(ei, E, offsets, rank, srcs);

    // layer 1 gather
    gather1_kernel<<<(N_NODES * 64 + 255) / 256, 256, 0, stream>>>(h1f8, ss1, sd1, offsets, srcs, b1, h1r);

    // layer 2 (gemm + logits fused)
    gemm2_kernel<<<(N_NODES + 63) / 64, 256, 0, stream>>>(h1r, W2, (ushort16*)h2b, as2, ad2, ss2, sd2);
    gather2_kernel<<<(N_NODES * 64 + 255) / 256, 256, 0, stream>>>(h2b, ss2, sd2, offsets, srcs, b2, out);
}

// Round 7
// 353.815 us; speedup vs baseline: 1.0529x; 1.0378x over previous
//
#include <hip/hip_runtime.h>
#include <math.h>

#define N_NODES 100000
#define F_IN    128
#define H1      8
#define C1      16
#define D1      128   // H1*C1
#define NCLS    40
#define NEG     0.2f

typedef unsigned int uint32;
typedef unsigned short ushort16;
typedef float v2f __attribute__((ext_vector_type(2)));
typedef __attribute__((ext_vector_type(8))) short bf16x8;   // 4 VGPRs, MFMA A/B frag
typedef __attribute__((ext_vector_type(4))) float f32x4;    // MFMA C/D frag

__device__ __forceinline__ ushort16 f2bf(float f) {
    unsigned int u = __float_as_uint(f);
    u += 0x7fffu + ((u >> 16) & 1u);          // round-to-nearest-even
    return (ushort16)(u >> 16);
}
__device__ __forceinline__ float bf_lo(uint32 p) { return __uint_as_float(p << 16); }
__device__ __forceinline__ float bf_hi(uint32 p) { return __uint_as_float(p & 0xffff0000u); }

#define NG 1563   // gemm blocks (64 rows each)

// W1 -> bf16 transposed+padded [128][136]; W2 -> bf16 transposed+padded
// [48][136] (cols 40-47 zero); also zeroes deg (replaces memset).
__global__ void prep_w_kernel(const float* __restrict__ W1,
                              const float* __restrict__ W2,
                              unsigned short* __restrict__ w1t,
                              unsigned short* __restrict__ w2t,
                              int* __restrict__ deg)
{
    int idx = blockIdx.x * 256 + threadIdx.x;
    if (idx < 16384) {
        int n = idx & 127, k = idx >> 7;        // coalesced read of W1[k][n]
        w1t[n * 136 + k] = f2bf(W1[k * 128 + n]);
    }
    if (idx < 6528) {                           // 48 x 136
        int c = idx / 136, k = idx - 136 * c;
        unsigned short v = 0;
        if (c < 40 && k < 128) v = f2bf(W2[k * 40 + c]);
        w2t[idx] = v;
    }
    if (idx < N_NODES) deg[idx] = 0;
}

// ---------------- fused: layer-1 MFMA GEMM(+logits) blocks + CSR-count ------
// Proven 1:4 interleave, 1 edge/thread: atomic-throughput-bound count blocks
// co-resident with LDS/MFMA-bound gemm blocks from t=0.
__global__ __launch_bounds__(256) void gemm1_count_kernel(
    const float* __restrict__ x, const unsigned short* __restrict__ w1t,
    uint32* __restrict__ h8,            // fp8 rows, N x 32 dwords
    const float* __restrict__ a_src, const float* __restrict__ a_dst,
    float* __restrict__ ssrc, float* __restrict__ sdst,
    const int* __restrict__ ei, int E,
    int* __restrict__ deg, int* __restrict__ rank)
{
    // 34816 B: holds W1^T bf16 [128][136] during MFMA, then hs fp32 [64][132]
    __shared__ __align__(16) uint32 wbuf[8704];
    const int bid = blockIdx.x;
    const int tid = threadIdx.x;
    const bool is_gemm = ((bid % 5) == 0) && (bid / 5 < NG);
    if (!is_gemm) {
        // ---------------- count path: rank[e] = old deg[dst]++ --------------
        int ng_before = bid / 5 + ((bid % 5) ? 1 : 0);   // gemm blocks < bid
        if (ng_before > NG) ng_before = NG;
        int c = bid - ng_before;
        long long e = (long long)c * 256 + tid;
        if (e < E) rank[e] = atomicAdd(&deg[ei[E + e]], 1);
        return;
    }
    const int row0 = (bid / 5) * 64;
    const int wid = tid >> 6, lane = tid & 63;

    // ---- A fragments straight from global: wave w owns rows 16w..16w+15.
    const int arow = row0 + wid * 16 + (lane & 15);
    const bool rowok = arow < N_NODES;
    const float* xp = x + (size_t)arow * 128 + 8 * (lane >> 4);
    float4 af0[4], af1[4];
#pragma unroll
    for (int s = 0; s < 4; ++s) {
        if (rowok) {
            af0[s] = *(const float4*)(xp + 32 * s);
            af1[s] = *(const float4*)(xp + 32 * s + 4);
        } else {
            af0[s] = make_float4(0.f, 0.f, 0.f, 0.f);
            af1[s] = make_float4(0.f, 0.f, 0.f, 0.f);
        }
    }
    // ---- stage W1^T bf16 into LDS (linear 34816 B copy, pad included) ----
    {
        const uint32* g = (const uint32*)w1t;
#pragma unroll
        for (int i = 0; i < 8; ++i)
            ((uint4*)wbuf)[tid + i * 256] = ((const uint4*)g)[tid + i * 256];
        wbuf[8192 + tid] = g[8192 + tid];
        wbuf[8448 + tid] = g[8448 + tid];
    }
    // ---- convert A to bf16 fragments (same k-order as B reads: 8g+j) ----
    bf16x8 a[4];
#pragma unroll
    for (int s = 0; s < 4; ++s) {
        a[s][0] = (short)f2bf(af0[s].x); a[s][1] = (short)f2bf(af0[s].y);
        a[s][2] = (short)f2bf(af0[s].z); a[s][3] = (short)f2bf(af0[s].w);
        a[s][4] = (short)f2bf(af1[s].x); a[s][5] = (short)f2bf(af1[s].y);
        a[s][6] = (short)f2bf(af1[s].z); a[s][7] = (short)f2bf(af1[s].w);
    }
    __syncthreads();
    // ---- K loop: 4 steps x 8 col-fragments = 32 MFMAs / wave ----
    f32x4 acc[8];
#pragma unroll
    for (int j = 0; j < 8; ++j)
#pragma unroll
        for (int r = 0; r < 4; ++r) acc[j][r] = 0.f;
    const unsigned short* wb = (const unsigned short*)wbuf;
    const int bc = lane & 15, ko = 8 * (lane >> 4);
#pragma unroll
    for (int s = 0; s < 4; ++s) {
#pragma unroll
        for (int j = 0; j < 8; ++j) {
            bf16x8 b = *(const bf16x8*)&wb[(16 * j + bc) * 136 + 32 * s + ko];
            acc[j] = __builtin_amdgcn_mfma_f32_16x16x32_bf16(a[s], b, acc[j], 0, 0, 0);
        }
    }
    __syncthreads();   // all MFMA operand reads of wbuf done
    // ---- write acc to hs[64][132] (C/D map: col=lane&15, row=(lane>>4)*4+r)
    float* hs = (float*)wbuf;
    const int cr0 = wid * 16 + 4 * (lane >> 4);
#pragma unroll
    for (int j = 0; j < 8; ++j)
#pragma unroll
        for (int r = 0; r < 4; ++r)
            hs[(cr0 + r) * 132 + 16 * j + bc] = acc[j][r];
    __syncthreads();
    // ---- fp8 pack: 64 rows x 16 uint2-groups, 4 tasks/thread ----
#pragma unroll
    for (int t = 0; t < 4; ++t) {
        int task = tid + t * 256;     // 0..1023
        int r = task >> 4, g = task & 15;
        if (row0 + r < N_NODES) {
            float4 va = *(const float4*)&hs[r * 132 + 8 * g];
            float4 vb = *(const float4*)&hs[r * 132 + 8 * g + 4];
            int p0 = __builtin_amdgcn_cvt_pk_fp8_f32(va.x, va.y, 0, false);
            p0     = __builtin_amdgcn_cvt_pk_fp8_f32(va.z, va.w, p0, true);
            int p1 = __builtin_amdgcn_cvt_pk_fp8_f32(vb.x, vb.y, 0, false);
            p1     = __builtin_amdgcn_cvt_pk_fp8_f32(vb.z, vb.w, p1, true);
            uint2 pk; pk.x = (uint32)p0; pk.y = (uint32)p1;
            ((uint2*)h8)[(size_t)(row0 + r) * 16 + g] = pk;
        }
    }
    // ---- logits: 64 rows x 8 heads = 512 tasks, 2 per thread ----
#pragma unroll
    for (int t = 0; t < 2; ++t) {
        int task = tid + t * 256;
        int r = task >> 3, hh = task & 7;
        if (row0 + r < N_NODES) {
            float as = 0.f, ad = 0.f;
#pragma unroll
            for (int c = 0; c < 16; ++c) {
                float v = hs[r * 132 + hh * 16 + c];
                as = fmaf(v, a_src[hh * 16 + c], as);
                ad = fmaf(v, a_dst[hh * 16 + c], ad);
            }
            ssrc[(row0 + r) * 8 + hh] = as;
            sdst[(row0 + r) * 8 + hh] = ad;
        }
    }
}

// block-local inclusive scan (256/block) + raw block sums
__global__ void scan1_kernel(const int* __restrict__ deg,
                             int* __restrict__ incl,
                             int* __restrict__ bsum)
{
    __shared__ int tmp[256];
    int i = blockIdx.x * 256 + threadIdx.x;
    int v = (i < N_NODES) ? deg[i] : 0;
    tmp[threadIdx.x] = v;
    __syncthreads();
    for (int o = 1; o < 256; o <<= 1) {
        int t = (threadIdx.x >= (unsigned)o) ? tmp[threadIdx.x - o] : 0;
        __syncthreads();
        tmp[threadIdx.x] += t;
        __syncthreads();
    }
    if (i < N_NODES) incl[i] = tmp[threadIdx.x];
    if (threadIdx.x == 255) bsum[blockIdx.x] = tmp[255];
}

// offsets[i+1] = incl[i] + prefix(bsum, block); each block sums its own
// prefix of the raw block sums — replaces scan2+scan3.
__global__ void scan3_kernel(const int* __restrict__ incl,
                             const int* __restrict__ bsum,
                             int* __restrict__ offsets)
{
    __shared__ int red[4];
    int pre = 0;
    for (int i = threadIdx.x; i < blockIdx.x; i += 256) pre += bsum[i];
#pragma unroll
    for (int o = 32; o > 0; o >>= 1) pre += __shfl_xor(pre, o);
    if ((threadIdx.x & 63) == 0) red[threadIdx.x >> 6] = pre;
    __syncthreads();
    int total = red[0] + red[1] + red[2] + red[3];
    int i = blockIdx.x * 256 + threadIdx.x;
    if (i < N_NODES) offsets[i + 1] = incl[i] + total;
    if (i == 0) offsets[0] = 0;
}

// atomic-free scatter using precomputed rank
__global__ void scatter_kernel(const int* __restrict__ ei, int E,
                               const int* __restrict__ offsets,
                               const int* __restrict__ rank,
                               int* __restrict__ srcs)
{
    int e = blockIdx.x * blockDim.x + threadIdx.x;
    if (e >= E) return;
    int s = ei[e], d = ei[E + e];
    srcs[offsets[d] + rank[e]] = s;
}

// ---------------- layer 1 gather: one wave per dst node (fp8 h rows) --------
// 128-thread blocks (2 waves): halves block-retire tail from degree variance.
__global__ void gather1_kernel(const uint32* __restrict__ h8,   // N x 32 dwords
                               const float* __restrict__ ssrc,
                               const float* __restrict__ sdst,
                               const int* __restrict__ offsets,
                               const int* __restrict__ srcs,
                               const float* __restrict__ b1,
                               float* __restrict__ out)
{
    __shared__ uint2 sw[2][64];
    int d = (blockIdx.x * blockDim.x + threadIdx.x) >> 6;
    int lane = threadIdx.x & 63;
    int wid = (threadIdx.x >> 6) & 1;
    if (d >= N_NODES) return;
    const int hw = lane & 7;            // head in weight phase
    const int half = lane >> 5;         // edge parity in accumulate phase
    const int u = lane & 31;            // dword in row: channels 4u..4u+3
    const int hc = u >> 2;              // head of my channels
    const float sd_w = sdst[d * H1 + hw];

    float acc0 = 0.f, acc1 = 0.f, acc2 = 0.f, acc3 = 0.f;
    float wsum = 0.f;

    // self-loop weight for my channel head
    float lgs = ssrc[d * H1 + hc] + sdst[d * H1 + hc];
    lgs = lgs >= 0.f ? lgs : NEG * lgs;
    const float ws_self = __expf(lgs);
    {   // only half 0 accumulates the self row (avoid double count)
        float m = (half == 0) ? ws_self : 0.f;
        uint32 p = h8[(size_t)d * 32 + u];
        v2f lo = __builtin_amdgcn_cvt_pk_f32_fp8((int)p, false);
        v2f hi = __builtin_amdgcn_cvt_pk_f32_fp8((int)p, true);
        acc0 = m * lo[0]; acc1 = m * lo[1];
        acc2 = m * hi[0]; acc3 = m * hi[1];
    }

    // (s,w) staging slot for my (half, head): read swp[16*t] = edge 2t+half
    const uint2* swp = &sw[wid][(half << 3) | hc];
    const int beg = offsets[d], end = offsets[d + 1];
    for (int base = beg; base < end; base += 8) {
        int cnt = end - base; if (cnt > 8) cnt = 8;
        int s_l = 0; float w_l = 0.f;
        if ((lane >> 3) < cnt) {
            s_l = srcs[base + (lane >> 3)];
            float lg = ssrc[s_l * H1 + hw] + sd_w;
            lg = lg >= 0.f ? lg : NEG * lg;
            w_l = __expf(lg);
        }
        wsum += w_l;
        sw[wid][lane] = make_uint2((uint32)s_l, __float_as_uint(w_l));
        asm volatile("s_waitcnt lgkmcnt(0)" ::: "memory");
#pragma unroll
        for (int t = 0; t < 4; ++t) {       // slots >= cnt carry w=0, s=0
            uint2 q = swp[16 * t];
            float w = __uint_as_float(q.y);
            uint32 p = h8[(size_t)q.x * 32 + u];
            v2f lo = __builtin_amdgcn_cvt_pk_f32_fp8((int)p, false);
            v2f hi = __builtin_amdgcn_cvt_pk_f32_fp8((int)p, true);
            acc0 = fmaf(w, lo[0], acc0);
            acc1 = fmaf(w, lo[1], acc1);
            acc2 = fmaf(w, hi[0], acc2);
            acc3 = fmaf(w, hi[1], acc3);
        }
    }
    // head-wise total: sum wsum over the 8 edge-slot groups (xor bits 3..5)
    wsum += __shfl_xor(wsum, 8);
    wsum += __shfl_xor(wsum, 16);
    wsum += __shfl_xor(wsum, 32);
    float ws = ws_self + __shfl(wsum, hc);
    // cross-half accumulator reduce
    acc0 += __shfl_xor(acc0, 32);
    acc1 += __shfl_xor(acc1, 32);
    acc2 += __shfl_xor(acc2, 32);
    acc3 += __shfl_xor(acc3, 32);
    if (half == 0) {
        float inv = 1.f / (ws + 1e-16f);
        float4 bb = ((const float4*)b1)[u];
        float4 r;
        r.x = fmaf(acc0, inv, bb.x); r.x = r.x > 0.f ? r.x : 0.f;
        r.y = fmaf(acc1, inv, bb.y); r.y = r.y > 0.f ? r.y : 0.f;
        r.z = fmaf(acc2, inv, bb.z); r.z = r.z > 0.f ? r.z : 0.f;
        r.w = fmaf(acc3, inv, bb.w); r.w = r.w > 0.f ? r.w : 0.f;
        ((float4*)(out + (size_t)d * D1))[u] = r;
    }
}

// ---------------- layer 2 GEMM (bf16 MFMA) + logits, fused ------------------
// A frags wave-private from global (like gemm1); B = W2^T bf16 [48][136] in
// LDS (pad cols 40-47 are zero). 12 MFMA/wave replaces 1280 VALU FMA/thread.
__global__ __launch_bounds__(256) void gemm2_kernel(
    const float* __restrict__ h, const unsigned short* __restrict__ w2t,
    ushort16* __restrict__ h2b,
    const float* __restrict__ a_src, const float* __restrict__ a_dst,
    float* __restrict__ ssrc, float* __restrict__ sdst)
{
    __shared__ __align__(16) unsigned short w2s[6528];   // 13056 B
    __shared__ float hs[64][132];
    const int row0 = blockIdx.x * 64;
    const int tid = threadIdx.x;
    const int wid = tid >> 6, lane = tid & 63;

    // ---- A fragments from global: wave w owns rows 16w..16w+15 ----
    const int arow = row0 + wid * 16 + (lane & 15);
    const bool rowok = arow < N_NODES;
    const float* xp = h + (size_t)arow * 128 + 8 * (lane >> 4);
    bf16x8 a[4];
#pragma unroll
    for (int s = 0; s < 4; ++s) {
        float4 v0 = make_float4(0.f, 0.f, 0.f, 0.f), v1 = v0;
        if (rowok) {
            v0 = *(const float4*)(xp + 32 * s);
            v1 = *(const float4*)(xp + 32 * s + 4);
        }
        a[s][0] = (short)f2bf(v0.x); a[s][1] = (short)f2bf(v0.y);
        a[s][2] = (short)f2bf(v0.z); a[s][3] = (short)f2bf(v0.w);
        a[s][4] = (short)f2bf(v1.x); a[s][5] = (short)f2bf(v1.y);
        a[s][6] = (short)f2bf(v1.z); a[s][7] = (short)f2bf(v1.w);
    }
    // ---- stage W2^T bf16 (3264 dwords) ----
    {
        const uint32* g = (const uint32*)w2t;
        uint32* wsd = (uint32*)w2s;
        for (int i = tid; i < 3264; i += 256) wsd[i] = g[i];
    }
    __syncthreads();
    // ---- 4 k-steps x 3 col-fragments = 12 MFMA / wave ----
    f32x4 acc[3];
#pragma unroll
    for (int j = 0; j < 3; ++j)
#pragma unroll
        for (int r = 0; r < 4; ++r) acc[j][r] = 0.f;
    const int bc = lane & 15, ko = 8 * (lane >> 4);
#pragma unroll
    for (int s = 0; s < 4; ++s) {
#pragma unroll
        for (int j = 0; j < 3; ++j) {
            bf16x8 b = *(const bf16x8*)&w2s[(16 * j + bc) * 136 + 32 * s + ko];
            acc[j] = __builtin_amdgcn_mfma_f32_16x16x32_bf16(a[s], b, acc[j], 0, 0, 0);
        }
    }
    // ---- write C: hs rows (for logits) + h2b bf16 (cols < 40) ----
    const int cr0 = wid * 16 + 4 * (lane >> 4);
#pragma unroll
    for (int j = 0; j < 3; ++j)
#pragma unroll
        for (int r = 0; r < 4; ++r) {
            int col = 16 * j + bc;
            int rr = cr0 + r;
            hs[rr][col] = acc[j][r];
            if (col < NCLS && row0 + rr < N_NODES)
                h2b[(size_t)(row0 + rr) * 40 + col] = f2bf(acc[j][r]);
        }
    __syncthreads();
    // ---- logits: 64 rows, 40 channels each ----
    if (tid < 64 && row0 + tid < N_NODES) {
        float as = 0.f, ad = 0.f;
#pragma unroll
        for (int c = 0; c < 40; ++c) {
            float v = hs[tid][c];
            as = fmaf(v, a_src[c], as);
            ad = fmaf(v, a_dst[c], ad);
        }
        ssrc[row0 + tid] = as;
        sdst[row0 + tid] = ad;
    }
}

// ---------------- layer 2 gather + log_softmax: one wave per node (bf16) ----
// 128-thread blocks (2 waves): halves block-retire tail.
__global__ void gather2_kernel(const uint32* __restrict__ h2b,  // N x 20 uints
                               const float* __restrict__ ssrc,
                               const float* __restrict__ sdst,
                               const int* __restrict__ offsets,
                               const int* __restrict__ srcs,
                               const float* __restrict__ b2,
                               float* __restrict__ out)
{
    __shared__ uint2 sw[2][64];
    __shared__ __align__(16) float4 pacc[2][64];
    int d = (blockIdx.x * blockDim.x + threadIdx.x) >> 6;
    int lane = threadIdx.x & 63;
    int wid = (threadIdx.x >> 6) & 1;
    if (d >= N_NODES) return;
    const float sd = sdst[d];
    const int g = lane / 10;              // group 0..6 (g<6 accumulate)
    const int c = lane - 10 * g;          // uint2 within row: channels 4c..4c+3
    const bool act = lane < 10;           // lanes that own the output
    const uint2* h2v = (const uint2*)h2b; // rows of 10 uint2
    float acc0 = 0.f, acc1 = 0.f, acc2 = 0.f, acc3 = 0.f, wl = 0.f;

    // self-loop (output lanes only)
    float ws_self;
    {
        float lg = ssrc[d] + sd; lg = lg >= 0.f ? lg : NEG * lg;
        ws_self = __expf(lg);
        if (act) {
            uint2 p = h2v[(size_t)d * 10 + lane];
            acc0 = ws_self * bf_lo(p.x); acc1 = ws_self * bf_hi(p.x);
            acc2 = ws_self * bf_lo(p.y); acc3 = ws_self * bf_hi(p.y);
        }
    }
    const int beg = offsets[d], end = offsets[d + 1];
    for (int base = beg; base < end; base += 64) {
        int cnt = end - base; if (cnt > 64) cnt = 64;
        int s_l = 0; float w_l = 0.f;
        if (lane < cnt) {
            s_l = srcs[base + lane];
            float lg = ssrc[s_l] + sd; lg = lg >= 0.f ? lg : NEG * lg;
            w_l = __expf(lg);
        }
        wl += w_l;
        sw[wid][lane] = make_uint2((uint32)s_l, __float_as_uint(w_l));
        asm volatile("s_waitcnt lgkmcnt(0)" ::: "memory");
        for (int j = 0; j < cnt; j += 6) {
            int jj = j + g;
            uint2 q = sw[wid][jj & 63];
            float w = ((g < 6) & (jj < cnt)) ? __uint_as_float(q.y) : 0.f;
            uint2 p = h2v[(size_t)q.x * 10 + c];
            acc0 = fmaf(w, bf_lo(p.x), acc0);
            acc1 = fmaf(w, bf_hi(p.x), acc1);
            acc2 = fmaf(w, bf_lo(p.y), acc2);
            acc3 = fmaf(w, bf_hi(p.y), acc3);
        }
    }
    // denominator: one full-wave reduce at the end
    float t = wl;
#pragma unroll
    for (int o = 32; o > 0; o >>= 1) t += __shfl_xor(t, o);
    float ws = ws_self + t;
    // cross-group accumulator reduce via LDS (partials at lanes c + 10k)
    float4 mine; mine.x = acc0; mine.y = acc1; mine.z = acc2; mine.w = acc3;
    pacc[wid][lane] = mine;
    asm volatile("s_waitcnt lgkmcnt(0)" ::: "memory");
    float l0 = -INFINITY, l1 = -INFINITY, l2 = -INFINITY, l3 = -INFINITY;
    if (act) {
        float4 s0 = pacc[wid][lane];
        float4 s1 = pacc[wid][lane + 10];
        float4 s2 = pacc[wid][lane + 20];
        float4 s3 = pacc[wid][lane + 30];
        float4 s4 = pacc[wid][lane + 40];
        float4 s5 = pacc[wid][lane + 50];
        float a0 = s0.x + s1.x + s2.x + s3.x + s4.x + s5.x;
        float a1 = s0.y + s1.y + s2.y + s3.y + s4.y + s5.y;
        float a2 = s0.z + s1.z + s2.z + s3.z + s4.z + s5.z;
        float a3 = s0.w + s1.w + s2.w + s3.w + s4.w + s5.w;
        float inv = 1.f / (ws + 1e-16f);
        l0 = fmaf(a0, inv, b2[4 * lane + 0]);
        l1 = fmaf(a1, inv, b2[4 * lane + 1]);
        l2 = fmaf(a2, inv, b2[4 * lane + 2]);
        l3 = fmaf(a3, inv, b2[4 * lane + 3]);
    }
    // softmax over 10 active lanes: 16-lane butterflies suffice
    float m = fmaxf(fmaxf(l0, l1), fmaxf(l2, l3));
#pragma unroll
    for (int o = 8; o > 0; o >>= 1) m = fmaxf(m, __shfl_xor(m, o));
    float ex = act ? (__expf(l0 - m) + __expf(l1 - m) + __expf(l2 - m) + __expf(l3 - m)) : 0.f;
#pragma unroll
    for (int o = 8; o > 0; o >>= 1) ex += __shfl_xor(ex, o);
    float lse = __logf(ex) + m;
    if (act) {
        float4 r;
        r.x = l0 - lse; r.y = l1 - lse; r.z = l2 - lse; r.w = l3 - lse;
        ((float4*)(out + (size_t)d * NCLS))[lane] = r;
    }
}

extern "C" void kernel_launch(void* const* d_in, const int* in_sizes, int n_in,
                              void* d_out, int out_size, void* d_ws, size_t ws_size,
                              hipStream_t stream)
{
    const float* x   = (const float*)d_in[0];
    const int*   ei  = (const int*)  d_in[1];
    const float* W1  = (const float*)d_in[2];
    const float* as1 = (const float*)d_in[3];
    const float* ad1 = (const float*)d_in[4];
    const float* b1  = (const float*)d_in[5];
    const float* W2  = (const float*)d_in[6];
    const float* as2 = (const float*)d_in[7];
    const float* ad2 = (const float*)d_in[8];
    const float* b2  = (const float*)d_in[9];
    float* out = (float*)d_out;
    const int E = in_sizes[1] / 2;

    float* ws = (float*)d_ws;
    size_t off = 0;
    uint32* h1f8 = (uint32*)(ws + off); off += (size_t)N_NODES * 32;  // fp8 N x 128
    float* h1r  = ws + off; off += (size_t)N_NODES * D1;
    float* ss1  = ws + off; off += (size_t)N_NODES * H1;
    float* sd1  = ws + off; off += (size_t)N_NODES * H1;
    uint32* h2b = (uint32*)(ws + off); off += (size_t)N_NODES * 20;   // bf16 N x 40
    float* ss2  = ws + off; off += N_NODES;
    float* sd2  = ws + off; off += N_NODES;
    unsigned short* w1t = (unsigned short*)(ws + off); off += 8704;   // bf16 W1^T [128][136]
    unsigned short* w2t = (unsigned short*)(ws + off); off += 3264;   // bf16 W2^T [48][136]
    int* ib = (int*)(ws + off);
    size_t ioff = 0;
    int* deg     = ib + ioff; ioff += N_NODES;      // zeroed in prep_w_kernel
    int* incl    = ib + ioff; ioff += N_NODES;
    int* offsets = ib + ioff; ioff += N_NODES + 1;
    int* bsum    = ib + ioff; ioff += 512;
    int* rank    = ib + ioff; ioff += E;
    int* srcs    = ib + ioff; ioff += E;

    const int nb = (N_NODES + 255) / 256;           // 391
    const int nc = (E + 255) / 256;                 // count blocks (6250)

    // W1/W2 -> bf16 transposed+padded + deg zeroing
    prep_w_kernel<<<nb, 256, 0, stream>>>(W1, W2, w1t, w2t, deg);

    // fused layer-1 MFMA gemm(+logits) + CSR count (proven 1:4 interleave)
    gemm1_count_kernel<<<NG + nc, 256, 0, stream>>>(x, w1t, h1f8, as1, ad1,
                                                    ss1, sd1, ei, E, deg, rank);
    // CSR finish
    scan1_kernel<<<nb, 256, 0, stream>>>(deg, incl, bsum);
    scan3_kernel<<<nb, 256, 0, stream>>>(incl, bsum, offsets);
    scatter_kernel<<<(E + 255) / 256, 256, 0, stream>>>(ei, E, offsets, rank, srcs);

    // layer 1 gather (128-thread blocks)
    gather1_kernel<<<(N_NODES * 64 + 127) / 128, 128, 0, stream>>>(h1f8, ss1, sd1, offsets, srcs, b1, h1r);

    // layer 2 (MFMA gemm + logits fused)
    gemm2_kernel<<<(N_NODES + 63) / 64, 256, 0, stream>>>(h1r, w2t, (ushort16*)h2b, as2, ad2, ss2, sd2);
    gather2_kernel<<<(N_NODES * 64 + 127) / 128, 128, 0, stream>>>(h2b, ss2, sd2, offsets, srcs, b2, out);
}

// Round 8
// 343.095 us; speedup vs baseline: 1.0858x; 1.0312x over previous
//
#include <hip/hip_runtime.h>
#include <math.h>

#define N_NODES 100000
#define F_IN    128
#define H1      8
#define C1      16
#define D1      128   // H1*C1
#define NCLS    40
#define NEG     0.2f

typedef unsigned int uint32;
typedef unsigned short ushort16;
typedef float v2f __attribute__((ext_vector_type(2)));
typedef __attribute__((ext_vector_type(8))) short bf16x8;   // 4 VGPRs, MFMA A/B frag
typedef __attribute__((ext_vector_type(4))) float f32x4;    // MFMA C/D frag

__device__ __forceinline__ ushort16 f2bf(float f) {
    unsigned int u = __float_as_uint(f);
    u += 0x7fffu + ((u >> 16) & 1u);          // round-to-nearest-even
    return (ushort16)(u >> 16);
}
__device__ __forceinline__ float bf_lo(uint32 p) { return __uint_as_float(p << 16); }
__device__ __forceinline__ float bf_hi(uint32 p) { return __uint_as_float(p & 0xffff0000u); }

#define NG 1563   // gemm blocks (64 rows each)

// W1 -> bf16 transposed+padded [128][136]; W2 -> bf16 transposed+padded
// [48][136] (cols 40-47 zero); also zeroes deg (replaces memset).
__global__ void prep_w_kernel(const float* __restrict__ W1,
                              const float* __restrict__ W2,
                              unsigned short* __restrict__ w1t,
                              unsigned short* __restrict__ w2t,
                              int* __restrict__ deg)
{
    int idx = blockIdx.x * 256 + threadIdx.x;
    if (idx < 16384) {
        int n = idx & 127, k = idx >> 7;        // coalesced read of W1[k][n]
        w1t[n * 136 + k] = f2bf(W1[k * 128 + n]);
    }
    if (idx < 6528) {                           // 48 x 136
        int c = idx / 136, k = idx - 136 * c;
        unsigned short v = 0;
        if (c < 40 && k < 128) v = f2bf(W2[k * 40 + c]);
        w2t[idx] = v;
    }
    if (idx < N_NODES) deg[idx] = 0;
}

// ---------------- fused: layer-1 MFMA GEMM(+logits) blocks + CSR-count ------
// Proven 1:4 interleave, 1 edge/thread: atomic-throughput-bound count blocks
// co-resident with LDS/MFMA-bound gemm blocks from t=0.
__global__ __launch_bounds__(256) void gemm1_count_kernel(
    const float* __restrict__ x, const unsigned short* __restrict__ w1t,
    uint32* __restrict__ h8,            // fp8 rows, N x 32 dwords
    const float* __restrict__ a_src, const float* __restrict__ a_dst,
    float* __restrict__ ssrc, float* __restrict__ sdst,
    const int* __restrict__ ei, int E,
    int* __restrict__ deg, int* __restrict__ rank)
{
    // 34816 B: holds W1^T bf16 [128][136] during MFMA, then hs fp32 [64][132]
    __shared__ __align__(16) uint32 wbuf[8704];
    const int bid = blockIdx.x;
    const int tid = threadIdx.x;
    const bool is_gemm = ((bid % 5) == 0) && (bid / 5 < NG);
    if (!is_gemm) {
        // ---------------- count path: rank[e] = old deg[dst]++ --------------
        int ng_before = bid / 5 + ((bid % 5) ? 1 : 0);   // gemm blocks < bid
        if (ng_before > NG) ng_before = NG;
        int c = bid - ng_before;
        long long e = (long long)c * 256 + tid;
        if (e < E) rank[e] = atomicAdd(&deg[ei[E + e]], 1);
        return;
    }
    const int row0 = (bid / 5) * 64;
    const int wid = tid >> 6, lane = tid & 63;

    // ---- A fragments straight from global: wave w owns rows 16w..16w+15.
    const int arow = row0 + wid * 16 + (lane & 15);
    const bool rowok = arow < N_NODES;
    const float* xp = x + (size_t)arow * 128 + 8 * (lane >> 4);
    float4 af0[4], af1[4];
#pragma unroll
    for (int s = 0; s < 4; ++s) {
        if (rowok) {
            af0[s] = *(const float4*)(xp + 32 * s);
            af1[s] = *(const float4*)(xp + 32 * s + 4);
        } else {
            af0[s] = make_float4(0.f, 0.f, 0.f, 0.f);
            af1[s] = make_float4(0.f, 0.f, 0.f, 0.f);
        }
    }
    // ---- stage W1^T bf16 into LDS (linear 34816 B copy, pad included) ----
    {
        const uint32* g = (const uint32*)w1t;
#pragma unroll
        for (int i = 0; i < 8; ++i)
            ((uint4*)wbuf)[tid + i * 256] = ((const uint4*)g)[tid + i * 256];
        wbuf[8192 + tid] = g[8192 + tid];
        wbuf[8448 + tid] = g[8448 + tid];
    }
    // ---- convert A to bf16 fragments (same k-order as B reads: 8g+j) ----
    bf16x8 a[4];
#pragma unroll
    for (int s = 0; s < 4; ++s) {
        a[s][0] = (short)f2bf(af0[s].x); a[s][1] = (short)f2bf(af0[s].y);
        a[s][2] = (short)f2bf(af0[s].z); a[s][3] = (short)f2bf(af0[s].w);
        a[s][4] = (short)f2bf(af1[s].x); a[s][5] = (short)f2bf(af1[s].y);
        a[s][6] = (short)f2bf(af1[s].z); a[s][7] = (short)f2bf(af1[s].w);
    }
    __syncthreads();
    // ---- K loop: 4 steps x 8 col-fragments = 32 MFMAs / wave ----
    f32x4 acc[8];
#pragma unroll
    for (int j = 0; j < 8; ++j)
#pragma unroll
        for (int r = 0; r < 4; ++r) acc[j][r] = 0.f;
    const unsigned short* wb = (const unsigned short*)wbuf;
    const int bc = lane & 15, ko = 8 * (lane >> 4);
#pragma unroll
    for (int s = 0; s < 4; ++s) {
#pragma unroll
        for (int j = 0; j < 8; ++j) {
            bf16x8 b = *(const bf16x8*)&wb[(16 * j + bc) * 136 + 32 * s + ko];
            acc[j] = __builtin_amdgcn_mfma_f32_16x16x32_bf16(a[s], b, acc[j], 0, 0, 0);
        }
    }
    __syncthreads();   // all MFMA operand reads of wbuf done
    // ---- write acc to hs[64][132] (C/D map: col=lane&15, row=(lane>>4)*4+r)
    float* hs = (float*)wbuf;
    const int cr0 = wid * 16 + 4 * (lane >> 4);
#pragma unroll
    for (int j = 0; j < 8; ++j)
#pragma unroll
        for (int r = 0; r < 4; ++r)
            hs[(cr0 + r) * 132 + 16 * j + bc] = acc[j][r];
    __syncthreads();
    // ---- fp8 pack: 64 rows x 16 uint2-groups, 4 tasks/thread ----
#pragma unroll
    for (int t = 0; t < 4; ++t) {
        int task = tid + t * 256;     // 0..1023
        int r = task >> 4, g = task & 15;
        if (row0 + r < N_NODES) {
            float4 va = *(const float4*)&hs[r * 132 + 8 * g];
            float4 vb = *(const float4*)&hs[r * 132 + 8 * g + 4];
            int p0 = __builtin_amdgcn_cvt_pk_fp8_f32(va.x, va.y, 0, false);
            p0     = __builtin_amdgcn_cvt_pk_fp8_f32(va.z, va.w, p0, true);
            int p1 = __builtin_amdgcn_cvt_pk_fp8_f32(vb.x, vb.y, 0, false);
            p1     = __builtin_amdgcn_cvt_pk_fp8_f32(vb.z, vb.w, p1, true);
            uint2 pk; pk.x = (uint32)p0; pk.y = (uint32)p1;
            ((uint2*)h8)[(size_t)(row0 + r) * 16 + g] = pk;
        }
    }
    // ---- logits: 64 rows x 8 heads = 512 tasks, 2 per thread ----
#pragma unroll
    for (int t = 0; t < 2; ++t) {
        int task = tid + t * 256;
        int r = task >> 3, hh = task & 7;
        if (row0 + r < N_NODES) {
            float as = 0.f, ad = 0.f;
#pragma unroll
            for (int c = 0; c < 16; ++c) {
                float v = hs[r * 132 + hh * 16 + c];
                as = fmaf(v, a_src[hh * 16 + c], as);
                ad = fmaf(v, a_dst[hh * 16 + c], ad);
            }
            ssrc[(row0 + r) * 8 + hh] = as;
            sdst[(row0 + r) * 8 + hh] = ad;
        }
    }
}

// block-local inclusive scan (256/block) + raw block sums
__global__ void scan1_kernel(const int* __restrict__ deg,
                             int* __restrict__ incl,
                             int* __restrict__ bsum)
{
    __shared__ int tmp[256];
    int i = blockIdx.x * 256 + threadIdx.x;
    int v = (i < N_NODES) ? deg[i] : 0;
    tmp[threadIdx.x] = v;
    __syncthreads();
    for (int o = 1; o < 256; o <<= 1) {
        int t = (threadIdx.x >= (unsigned)o) ? tmp[threadIdx.x - o] : 0;
        __syncthreads();
        tmp[threadIdx.x] += t;
        __syncthreads();
    }
    if (i < N_NODES) incl[i] = tmp[threadIdx.x];
    if (threadIdx.x == 255) bsum[blockIdx.x] = tmp[255];
}

// offsets[i+1] = incl[i] + prefix(bsum, block); each block sums its own
// prefix of the raw block sums — replaces scan2+scan3.
__global__ void scan3_kernel(const int* __restrict__ incl,
                             const int* __restrict__ bsum,
                             int* __restrict__ offsets)
{
    __shared__ int red[4];
    int pre = 0;
    for (int i = threadIdx.x; i < blockIdx.x; i += 256) pre += bsum[i];
#pragma unroll
    for (int o = 32; o > 0; o >>= 1) pre += __shfl_xor(pre, o);
    if ((threadIdx.x & 63) == 0) red[threadIdx.x >> 6] = pre;
    __syncthreads();
    int total = red[0] + red[1] + red[2] + red[3];
    int i = blockIdx.x * 256 + threadIdx.x;
    if (i < N_NODES) offsets[i + 1] = incl[i] + total;
    if (i == 0) offsets[0] = 0;
}

// atomic-free scatter using precomputed rank
__global__ void scatter_kernel(const int* __restrict__ ei, int E,
                               const int* __restrict__ offsets,
                               const int* __restrict__ rank,
                               int* __restrict__ srcs)
{
    int e = blockIdx.x * blockDim.x + threadIdx.x;
    if (e >= E) return;
    int s = ei[e], d = ei[E + e];
    srcs[offsets[d] + rank[e]] = s;
}

// ---------------- layer 1 gather: one wave per dst node (fp8 h rows) --------
// 128-thread blocks (2 waves). Output h1 stored as PACKED BF16 (uint2/lane):
// numerically identical to old fp32 path (gemm2 bf16-converted anyway),
// halves h1 write+read traffic.
__global__ void gather1_kernel(const uint32* __restrict__ h8,   // N x 32 dwords
                               const float* __restrict__ ssrc,
                               const float* __restrict__ sdst,
                               const int* __restrict__ offsets,
                               const int* __restrict__ srcs,
                               const float* __restrict__ b1,
                               uint32* __restrict__ h1b)        // N x 64 dwords
{
    __shared__ uint2 sw[2][64];
    int d = (blockIdx.x * blockDim.x + threadIdx.x) >> 6;
    int lane = threadIdx.x & 63;
    int wid = (threadIdx.x >> 6) & 1;
    if (d >= N_NODES) return;
    const int hw = lane & 7;            // head in weight phase
    const int half = lane >> 5;         // edge parity in accumulate phase
    const int u = lane & 31;            // dword in row: channels 4u..4u+3
    const int hc = u >> 2;              // head of my channels
    const float sd_w = sdst[d * H1 + hw];

    float acc0 = 0.f, acc1 = 0.f, acc2 = 0.f, acc3 = 0.f;
    float wsum = 0.f;

    // self-loop weight for my channel head
    float lgs = ssrc[d * H1 + hc] + sdst[d * H1 + hc];
    lgs = lgs >= 0.f ? lgs : NEG * lgs;
    const float ws_self = __expf(lgs);
    {   // only half 0 accumulates the self row (avoid double count)
        float m = (half == 0) ? ws_self : 0.f;
        uint32 p = h8[(size_t)d * 32 + u];
        v2f lo = __builtin_amdgcn_cvt_pk_f32_fp8((int)p, false);
        v2f hi = __builtin_amdgcn_cvt_pk_f32_fp8((int)p, true);
        acc0 = m * lo[0]; acc1 = m * lo[1];
        acc2 = m * hi[0]; acc3 = m * hi[1];
    }

    // (s,w) staging slot for my (half, head): read swp[16*t] = edge 2t+half
    const uint2* swp = &sw[wid][(half << 3) | hc];
    const int beg = offsets[d], end = offsets[d + 1];
    for (int base = beg; base < end; base += 8) {
        int cnt = end - base; if (cnt > 8) cnt = 8;
        int s_l = 0; float w_l = 0.f;
        if ((lane >> 3) < cnt) {
            s_l = srcs[base + (lane >> 3)];
            float lg = ssrc[s_l * H1 + hw] + sd_w;
            lg = lg >= 0.f ? lg : NEG * lg;
            w_l = __expf(lg);
        }
        wsum += w_l;
        sw[wid][lane] = make_uint2((uint32)s_l, __float_as_uint(w_l));
        asm volatile("s_waitcnt lgkmcnt(0)" ::: "memory");
#pragma unroll
        for (int t = 0; t < 4; ++t) {       // slots >= cnt carry w=0, s=0
            uint2 q = swp[16 * t];
            float w = __uint_as_float(q.y);
            uint32 p = h8[(size_t)q.x * 32 + u];
            v2f lo = __builtin_amdgcn_cvt_pk_f32_fp8((int)p, false);
            v2f hi = __builtin_amdgcn_cvt_pk_f32_fp8((int)p, true);
            acc0 = fmaf(w, lo[0], acc0);
            acc1 = fmaf(w, lo[1], acc1);
            acc2 = fmaf(w, hi[0], acc2);
            acc3 = fmaf(w, hi[1], acc3);
        }
    }
    // head-wise total: sum wsum over the 8 edge-slot groups (xor bits 3..5)
    wsum += __shfl_xor(wsum, 8);
    wsum += __shfl_xor(wsum, 16);
    wsum += __shfl_xor(wsum, 32);
    float ws = ws_self + __shfl(wsum, hc);
    // cross-half accumulator reduce
    acc0 += __shfl_xor(acc0, 32);
    acc1 += __shfl_xor(acc1, 32);
    acc2 += __shfl_xor(acc2, 32);
    acc3 += __shfl_xor(acc3, 32);
    if (half == 0) {
        float inv = 1.f / (ws + 1e-16f);
        float4 bb = ((const float4*)b1)[u];
        float4 r;
        r.x = fmaf(acc0, inv, bb.x); r.x = r.x > 0.f ? r.x : 0.f;
        r.y = fmaf(acc1, inv, bb.y); r.y = r.y > 0.f ? r.y : 0.f;
        r.z = fmaf(acc2, inv, bb.z); r.z = r.z > 0.f ? r.z : 0.f;
        r.w = fmaf(acc3, inv, bb.w); r.w = r.w > 0.f ? r.w : 0.f;
        uint32 p0 = ((uint32)f2bf(r.y) << 16) | (uint32)f2bf(r.x);
        uint32 p1 = ((uint32)f2bf(r.w) << 16) | (uint32)f2bf(r.z);
        ((uint2*)(h1b + (size_t)d * 64))[u] = make_uint2(p0, p1);
    }
}

// ---------------- layer 2 GEMM (bf16 MFMA) + logits, fused ------------------
// A frags = direct uint4 loads from packed-bf16 h1b (no cvt); B = W2^T bf16
// [48][136] in LDS. Logits from MFMA accumulators via 16-lane butterflies —
// no hs LDS at all (13 KB total -> 8 blocks/CU).
__global__ __launch_bounds__(256) void gemm2_kernel(
    const uint32* __restrict__ h1b, const unsigned short* __restrict__ w2t,
    ushort16* __restrict__ h2b,
    const float* __restrict__ a_src, const float* __restrict__ a_dst,
    float* __restrict__ ssrc, float* __restrict__ sdst)
{
    __shared__ __align__(16) unsigned short w2s[6528];   // 13056 B
    const int row0 = blockIdx.x * 64;
    const int tid = threadIdx.x;
    const int wid = tid >> 6, lane = tid & 63;
    const int bc = lane & 15, g = lane >> 4;

    // ---- stage W2^T bf16 (3264 dwords) ----
    {
        const uint32* gs = (const uint32*)w2t;
        uint32* wsd = (uint32*)w2s;
        for (int i = tid; i < 3264; i += 256) wsd[i] = gs[i];
    }
    // ---- A fragments: wave w owns rows 16w..16w+15, direct bf16 loads ----
    const int arow = row0 + wid * 16 + bc;
    const bool rowok = arow < N_NODES;
    bf16x8 a[4];
#pragma unroll
    for (int s = 0; s < 4; ++s) {
        uint4 v = make_uint4(0u, 0u, 0u, 0u);
        if (rowok) v = *(const uint4*)&h1b[(size_t)arow * 64 + 16 * s + 4 * g];
        a[s] = *(bf16x8*)&v;
    }
    __syncthreads();
    // ---- 4 k-steps x 3 col-fragments = 12 MFMA / wave ----
    f32x4 acc[3];
#pragma unroll
    for (int j = 0; j < 3; ++j)
#pragma unroll
        for (int r = 0; r < 4; ++r) acc[j][r] = 0.f;
#pragma unroll
    for (int s = 0; s < 4; ++s) {
#pragma unroll
        for (int j = 0; j < 3; ++j) {
            bf16x8 b = *(const bf16x8*)&w2s[(16 * j + bc) * 136 + 32 * s + 8 * g];
            acc[j] = __builtin_amdgcn_mfma_f32_16x16x32_bf16(a[s], b, acc[j], 0, 0, 0);
        }
    }
    // ---- h2b bf16 write (C/D map: col=16j+bc, row=cr0+r) ----
    const int cr0 = wid * 16 + 4 * g;
#pragma unroll
    for (int j = 0; j < 3; ++j)
#pragma unroll
        for (int r = 0; r < 4; ++r) {
            int col = 16 * j + bc;
            int rr = cr0 + r;
            if (col < NCLS && row0 + rr < N_NODES)
                h2b[(size_t)(row0 + rr) * 40 + col] = f2bf(acc[j][r]);
        }
    // ---- logits via bc-butterflies: 16 bc-lanes hold all cols of 4 rows ----
    float avs[3], avd[3];
#pragma unroll
    for (int j = 0; j < 3; ++j) {
        int col = 16 * j + bc;
        avs[j] = (col < NCLS) ? a_src[col] : 0.f;
        avd[j] = (col < NCLS) ? a_dst[col] : 0.f;
    }
    float ps[4], pd[4];
#pragma unroll
    for (int r = 0; r < 4; ++r) {
        float s_ = acc[0][r] * avs[0];
        s_ = fmaf(acc[1][r], avs[1], s_);
        s_ = fmaf(acc[2][r], avs[2], s_);
        float d_ = acc[0][r] * avd[0];
        d_ = fmaf(acc[1][r], avd[1], d_);
        d_ = fmaf(acc[2][r], avd[2], d_);
        ps[r] = s_; pd[r] = d_;
    }
#pragma unroll
    for (int o = 1; o < 16; o <<= 1) {
#pragma unroll
        for (int r = 0; r < 4; ++r) {
            ps[r] += __shfl_xor(ps[r], o);
            pd[r] += __shfl_xor(pd[r], o);
        }
    }
    if (bc < 4) {
        int row = row0 + cr0 + bc;
        if (row < N_NODES) {
            float vs = bc == 0 ? ps[0] : bc == 1 ? ps[1] : bc == 2 ? ps[2] : ps[3];
            float vd = bc == 0 ? pd[0] : bc == 1 ? pd[1] : bc == 2 ? pd[2] : pd[3];
            ssrc[row] = vs;
            sdst[row] = vd;
        }
    }
}

// ---------------- layer 2 gather + log_softmax: one wave per node (bf16) ----
// 128-thread blocks (2 waves).
__global__ void gather2_kernel(const uint32* __restrict__ h2b,  // N x 20 uints
                               const float* __restrict__ ssrc,
                               const float* __restrict__ sdst,
                               const int* __restrict__ offsets,
                               const int* __restrict__ srcs,
                               const float* __restrict__ b2,
                               float* __restrict__ out)
{
    __shared__ uint2 sw[2][64];
    __shared__ __align__(16) float4 pacc[2][64];
    int d = (blockIdx.x * blockDim.x + threadIdx.x) >> 6;
    int lane = threadIdx.x & 63;
    int wid = (threadIdx.x >> 6) & 1;
    if (d >= N_NODES) return;
    const float sd = sdst[d];
    const int g = lane / 10;              // group 0..6 (g<6 accumulate)
    const int c = lane - 10 * g;          // uint2 within row: channels 4c..4c+3
    const bool act = lane < 10;           // lanes that own the output
    const uint2* h2v = (const uint2*)h2b; // rows of 10 uint2
    float acc0 = 0.f, acc1 = 0.f, acc2 = 0.f, acc3 = 0.f, wl = 0.f;

    // self-loop (output lanes only)
    float ws_self;
    {
        float lg = ssrc[d] + sd; lg = lg >= 0.f ? lg : NEG * lg;
        ws_self = __expf(lg);
        if (act) {
            uint2 p = h2v[(size_t)d * 10 + lane];
            acc0 = ws_self * bf_lo(p.x); acc1 = ws_self * bf_hi(p.x);
            acc2 = ws_self * bf_lo(p.y); acc3 = ws_self * bf_hi(p.y);
        }
    }
    const int beg = offsets[d], end = offsets[d + 1];
    for (int base = beg; base < end; base += 64) {
        int cnt = end - base; if (cnt > 64) cnt = 64;
        int s_l = 0; float w_l = 0.f;
        if (lane < cnt) {
            s_l = srcs[base + lane];
            float lg = ssrc[s_l] + sd; lg = lg >= 0.f ? lg : NEG * lg;
            w_l = __expf(lg);
        }
        wl += w_l;
        sw[wid][lane] = make_uint2((uint32)s_l, __float_as_uint(w_l));
        asm volatile("s_waitcnt lgkmcnt(0)" ::: "memory");
        for (int j = 0; j < cnt; j += 6) {
            int jj = j + g;
            uint2 q = sw[wid][jj & 63];
            float w = ((g < 6) & (jj < cnt)) ? __uint_as_float(q.y) : 0.f;
            uint2 p = h2v[(size_t)q.x * 10 + c];
            acc0 = fmaf(w, bf_lo(p.x), acc0);
            acc1 = fmaf(w, bf_hi(p.x), acc1);
            acc2 = fmaf(w, bf_lo(p.y), acc2);
            acc3 = fmaf(w, bf_hi(p.y), acc3);
        }
    }
    // denominator: one full-wave reduce at the end
    float t = wl;
#pragma unroll
    for (int o = 32; o > 0; o >>= 1) t += __shfl_xor(t, o);
    float ws = ws_self + t;
    // cross-group accumulator reduce via LDS (partials at lanes c + 10k)
    float4 mine; mine.x = acc0; mine.y = acc1; mine.z = acc2; mine.w = acc3;
    pacc[wid][lane] = mine;
    asm volatile("s_waitcnt lgkmcnt(0)" ::: "memory");
    float l0 = -INFINITY, l1 = -INFINITY, l2 = -INFINITY, l3 = -INFINITY;
    if (act) {
        float4 s0 = pacc[wid][lane];
        float4 s1 = pacc[wid][lane + 10];
        float4 s2 = pacc[wid][lane + 20];
        float4 s3 = pacc[wid][lane + 30];
        float4 s4 = pacc[wid][lane + 40];
        float4 s5 = pacc[wid][lane + 50];
        float a0 = s0.x + s1.x + s2.x + s3.x + s4.x + s5.x;
        float a1 = s0.y + s1.y + s2.y + s3.y + s4.y + s5.y;
        float a2 = s0.z + s1.z + s2.z + s3.z + s4.z + s5.z;
        float a3 = s0.w + s1.w + s2.w + s3.w + s4.w + s5.w;
        float inv = 1.f / (ws + 1e-16f);
        l0 = fmaf(a0, inv, b2[4 * lane + 0]);
        l1 = fmaf(a1, inv, b2[4 * lane + 1]);
        l2 = fmaf(a2, inv, b2[4 * lane + 2]);
        l3 = fmaf(a3, inv, b2[4 * lane + 3]);
    }
    // softmax over 10 active lanes: 16-lane butterflies suffice
    float m = fmaxf(fmaxf(l0, l1), fmaxf(l2, l3));
#pragma unroll
    for (int o = 8; o > 0; o >>= 1) m = fmaxf(m, __shfl_xor(m, o));
    float ex = act ? (__expf(l0 - m) + __expf(l1 - m) + __expf(l2 - m) + __expf(l3 - m)) : 0.f;
#pragma unroll
    for (int o = 8; o > 0; o >>= 1) ex += __shfl_xor(ex, o);
    float lse = __logf(ex) + m;
    if (act) {
        float4 r;
        r.x = l0 - lse; r.y = l1 - lse; r.z = l2 - lse; r.w = l3 - lse;
        ((float4*)(out + (size_t)d * NCLS))[lane] = r;
    }
}

extern "C" void kernel_launch(void* const* d_in, const int* in_sizes, int n_in,
                              void* d_out, int out_size, void* d_ws, size_t ws_size,
                              hipStream_t stream)
{
    const float* x   = (const float*)d_in[0];
    const int*   ei  = (const int*)  d_in[1];
    const float* W1  = (const float*)d_in[2];
    const float* as1 = (const float*)d_in[3];
    const float* ad1 = (const float*)d_in[4];
    const float* b1  = (const float*)d_in[5];
    const float* W2  = (const float*)d_in[6];
    const float* as2 = (const float*)d_in[7];
    const float* ad2 = (const float*)d_in[8];
    const float* b2  = (const float*)d_in[9];
    float* out = (float*)d_out;
    const int E = in_sizes[1] / 2;

    float* ws = (float*)d_ws;
    size_t off = 0;
    uint32* h1f8 = (uint32*)(ws + off); off += (size_t)N_NODES * 32;  // fp8 N x 128
    uint32* h1b = (uint32*)(ws + off); off += (size_t)N_NODES * 64;   // bf16 N x 128 packed
    float* ss1  = ws + off; off += (size_t)N_NODES * H1;
    float* sd1  = ws + off; off += (size_t)N_NODES * H1;
    uint32* h2b = (uint32*)(ws + off); off += (size_t)N_NODES * 20;   // bf16 N x 40
    float* ss2  = ws + off; off += N_NODES;
    float* sd2  = ws + off; off += N_NODES;
    unsigned short* w1t = (unsigned short*)(ws + off); off += 8704;   // bf16 W1^T [128][136]
    unsigned short* w2t = (unsigned short*)(ws + off); off += 3264;   // bf16 W2^T [48][136]
    int* ib = (int*)(ws + off);
    size_t ioff = 0;
    int* deg     = ib + ioff; ioff += N_NODES;      // zeroed in prep_w_kernel
    int* incl    = ib + ioff; ioff += N_NODES;
    int* offsets = ib + ioff; ioff += N_NODES + 1;
    int* bsum    = ib + ioff; ioff += 512;
    int* rank    = ib + ioff; ioff += E;
    int* srcs    = ib + ioff; ioff += E;

    const int nb = (N_NODES + 255) / 256;           // 391
    const int nc = (E + 255) / 256;                 // count blocks (6250)

    // W1/W2 -> bf16 transposed+padded + deg zeroing
    prep_w_kernel<<<nb, 256, 0, stream>>>(W1, W2, w1t, w2t, deg);

    // fused layer-1 MFMA gemm(+logits) + CSR count (proven 1:4 interleave)
    gemm1_count_kernel<<<NG + nc, 256, 0, stream>>>(x, w1t, h1f8, as1, ad1,
                                                    ss1, sd1, ei, E, deg, rank);
    // CSR finish
    scan1_kernel<<<nb, 256, 0, stream>>>(deg, incl, bsum);
    scan3_kernel<<<nb, 256, 0, stream>>>(incl, bsum, offsets);
    scatter_kernel<<<(E + 255) / 256, 256, 0, stream>>>(ei, E, offsets, rank, srcs);

    // layer 1 gather (128-thread blocks, bf16-packed output)
    gather1_kernel<<<(N_NODES * 64 + 127) / 128, 128, 0, stream>>>(h1f8, ss1, sd1, offsets, srcs, b1, h1b);

    // layer 2 (MFMA gemm + shuffle logits fused)
    gemm2_kernel<<<(N_NODES + 63) / 64, 256, 0, stream>>>(h1b, w2t, (ushort16*)h2b, as2, ad2, ss2, sd2);
    gather2_kernel<<<(N_NODES * 64 + 127) / 128, 128, 0, stream>>>(h2b, ss2, sd2, offsets, srcs, b2, out);
}

// Round 9
// 340.906 us; speedup vs baseline: 1.0928x; 1.0064x over previous
//
#include <hip/hip_runtime.h>
#include <math.h>

#define N_NODES 100000
#define F_IN    128
#define H1      8
#define C1      16
#define D1      128   // H1*C1
#define NCLS    40
#define NEG     0.2f

typedef unsigned int uint32;
typedef unsigned short ushort16;
typedef float v2f __attribute__((ext_vector_type(2)));
typedef __attribute__((ext_vector_type(8))) short bf16x8;   // 4 VGPRs, MFMA A/B frag
typedef __attribute__((ext_vector_type(4))) float f32x4;    // MFMA C/D frag

__device__ __forceinline__ ushort16 f2bf(float f) {
    unsigned int u = __float_as_uint(f);
    u += 0x7fffu + ((u >> 16) & 1u);          // round-to-nearest-even
    return (ushort16)(u >> 16);
}
__device__ __forceinline__ float bf_lo(uint32 p) { return __uint_as_float(p << 16); }
__device__ __forceinline__ float bf_hi(uint32 p) { return __uint_as_float(p & 0xffff0000u); }

#define NG 1563   // gemm blocks (64 rows each)

// W1 -> bf16 transposed+padded [128][136]; W2 -> bf16 transposed+padded
// [48][136] (cols 40-47 zero); also zeroes deg (replaces memset).
__global__ void prep_w_kernel(const float* __restrict__ W1,
                              const float* __restrict__ W2,
                              unsigned short* __restrict__ w1t,
                              unsigned short* __restrict__ w2t,
                              int* __restrict__ deg)
{
    int idx = blockIdx.x * 256 + threadIdx.x;
    if (idx < 16384) {
        int n = idx & 127, k = idx >> 7;        // coalesced read of W1[k][n]
        w1t[n * 136 + k] = f2bf(W1[k * 128 + n]);
    }
    if (idx < 6528) {                           // 48 x 136
        int c = idx / 136, k = idx - 136 * c;
        unsigned short v = 0;
        if (c < 40 && k < 128) v = f2bf(W2[k * 40 + c]);
        w2t[idx] = v;
    }
    if (idx < N_NODES) deg[idx] = 0;
}

// ---------------- fused: layer-1 MFMA GEMM(+logits) blocks + CSR-count ------
// Proven 1:4 interleave, 1 edge/thread: atomic-throughput-bound count blocks
// co-resident with LDS/MFMA-bound gemm blocks from t=0.
__global__ __launch_bounds__(256) void gemm1_count_kernel(
    const float* __restrict__ x, const unsigned short* __restrict__ w1t,
    uint32* __restrict__ h8,            // fp8 rows, N x 32 dwords
    const float* __restrict__ a_src, const float* __restrict__ a_dst,
    float* __restrict__ ssrc, float* __restrict__ sdst,
    const int* __restrict__ ei, int E,
    int* __restrict__ deg, int* __restrict__ rank)
{
    // 34816 B: holds W1^T bf16 [128][136] during MFMA, then hs fp32 [64][132]
    __shared__ __align__(16) uint32 wbuf[8704];
    const int bid = blockIdx.x;
    const int tid = threadIdx.x;
    const bool is_gemm = ((bid % 5) == 0) && (bid / 5 < NG);
    if (!is_gemm) {
        // ---------------- count path: rank[e] = old deg[dst]++ --------------
        int ng_before = bid / 5 + ((bid % 5) ? 1 : 0);   // gemm blocks < bid
        if (ng_before > NG) ng_before = NG;
        int c = bid - ng_before;
        long long e = (long long)c * 256 + tid;
        if (e < E) rank[e] = atomicAdd(&deg[ei[E + e]], 1);
        return;
    }
    const int row0 = (bid / 5) * 64;
    const int wid = tid >> 6, lane = tid & 63;

    // ---- A fragments straight from global: wave w owns rows 16w..16w+15.
    const int arow = row0 + wid * 16 + (lane & 15);
    const bool rowok = arow < N_NODES;
    const float* xp = x + (size_t)arow * 128 + 8 * (lane >> 4);
    float4 af0[4], af1[4];
#pragma unroll
    for (int s = 0; s < 4; ++s) {
        if (rowok) {
            af0[s] = *(const float4*)(xp + 32 * s);
            af1[s] = *(const float4*)(xp + 32 * s + 4);
        } else {
            af0[s] = make_float4(0.f, 0.f, 0.f, 0.f);
            af1[s] = make_float4(0.f, 0.f, 0.f, 0.f);
        }
    }
    // ---- stage W1^T bf16 into LDS (linear 34816 B copy, pad included) ----
    {
        const uint32* g = (const uint32*)w1t;
#pragma unroll
        for (int i = 0; i < 8; ++i)
            ((uint4*)wbuf)[tid + i * 256] = ((const uint4*)g)[tid + i * 256];
        wbuf[8192 + tid] = g[8192 + tid];
        wbuf[8448 + tid] = g[8448 + tid];
    }
    // ---- convert A to bf16 fragments (same k-order as B reads: 8g+j) ----
    bf16x8 a[4];
#pragma unroll
    for (int s = 0; s < 4; ++s) {
        a[s][0] = (short)f2bf(af0[s].x); a[s][1] = (short)f2bf(af0[s].y);
        a[s][2] = (short)f2bf(af0[s].z); a[s][3] = (short)f2bf(af0[s].w);
        a[s][4] = (short)f2bf(af1[s].x); a[s][5] = (short)f2bf(af1[s].y);
        a[s][6] = (short)f2bf(af1[s].z); a[s][7] = (short)f2bf(af1[s].w);
    }
    __syncthreads();
    // ---- K loop: 4 steps x 8 col-fragments = 32 MFMAs / wave ----
    f32x4 acc[8];
#pragma unroll
    for (int j = 0; j < 8; ++j)
#pragma unroll
        for (int r = 0; r < 4; ++r) acc[j][r] = 0.f;
    const unsigned short* wb = (const unsigned short*)wbuf;
    const int bc = lane & 15, ko = 8 * (lane >> 4);
#pragma unroll
    for (int s = 0; s < 4; ++s) {
#pragma unroll
        for (int j = 0; j < 8; ++j) {
            bf16x8 b = *(const bf16x8*)&wb[(16 * j + bc) * 136 + 32 * s + ko];
            acc[j] = __builtin_amdgcn_mfma_f32_16x16x32_bf16(a[s], b, acc[j], 0, 0, 0);
        }
    }
    __syncthreads();   // all MFMA operand reads of wbuf done
    // ---- write acc to hs[64][132] (C/D map: col=lane&15, row=(lane>>4)*4+r)
    float* hs = (float*)wbuf;
    const int cr0 = wid * 16 + 4 * (lane >> 4);
#pragma unroll
    for (int j = 0; j < 8; ++j)
#pragma unroll
        for (int r = 0; r < 4; ++r)
            hs[(cr0 + r) * 132 + 16 * j + bc] = acc[j][r];
    __syncthreads();
    // ---- fp8 pack: 64 rows x 16 uint2-groups, 4 tasks/thread ----
#pragma unroll
    for (int t = 0; t < 4; ++t) {
        int task = tid + t * 256;     // 0..1023
        int r = task >> 4, g = task & 15;
        if (row0 + r < N_NODES) {
            float4 va = *(const float4*)&hs[r * 132 + 8 * g];
            float4 vb = *(const float4*)&hs[r * 132 + 8 * g + 4];
            int p0 = __builtin_amdgcn_cvt_pk_fp8_f32(va.x, va.y, 0, false);
            p0     = __builtin_amdgcn_cvt_pk_fp8_f32(va.z, va.w, p0, true);
            int p1 = __builtin_amdgcn_cvt_pk_fp8_f32(vb.x, vb.y, 0, false);
            p1     = __builtin_amdgcn_cvt_pk_fp8_f32(vb.z, vb.w, p1, true);
            uint2 pk; pk.x = (uint32)p0; pk.y = (uint32)p1;
            ((uint2*)h8)[(size_t)(row0 + r) * 16 + g] = pk;
        }
    }
    // ---- logits: 64 rows x 8 heads = 512 tasks, 2 per thread ----
#pragma unroll
    for (int t = 0; t < 2; ++t) {
        int task = tid + t * 256;
        int r = task >> 3, hh = task & 7;
        if (row0 + r < N_NODES) {
            float as = 0.f, ad = 0.f;
#pragma unroll
            for (int c = 0; c < 16; ++c) {
                float v = hs[r * 132 + hh * 16 + c];
                as = fmaf(v, a_src[hh * 16 + c], as);
                ad = fmaf(v, a_dst[hh * 16 + c], ad);
            }
            ssrc[(row0 + r) * 8 + hh] = as;
            sdst[(row0 + r) * 8 + hh] = ad;
        }
    }
}

// block-local inclusive scan (256/block) + raw block sums
__global__ void scan1_kernel(const int* __restrict__ deg,
                             int* __restrict__ incl,
                             int* __restrict__ bsum)
{
    __shared__ int tmp[256];
    int i = blockIdx.x * 256 + threadIdx.x;
    int v = (i < N_NODES) ? deg[i] : 0;
    tmp[threadIdx.x] = v;
    __syncthreads();
    for (int o = 1; o < 256; o <<= 1) {
        int t = (threadIdx.x >= (unsigned)o) ? tmp[threadIdx.x - o] : 0;
        __syncthreads();
        tmp[threadIdx.x] += t;
        __syncthreads();
    }
    if (i < N_NODES) incl[i] = tmp[threadIdx.x];
    if (threadIdx.x == 255) bsum[blockIdx.x] = tmp[255];
}

// offsets[i+1] = incl[i] + prefix(bsum, block); each block sums its own
// prefix of the raw block sums — replaces scan2+scan3.
__global__ void scan3_kernel(const int* __restrict__ incl,
                             const int* __restrict__ bsum,
                             int* __restrict__ offsets)
{
    __shared__ int red[4];
    int pre = 0;
    for (int i = threadIdx.x; i < blockIdx.x; i += 256) pre += bsum[i];
#pragma unroll
    for (int o = 32; o > 0; o >>= 1) pre += __shfl_xor(pre, o);
    if ((threadIdx.x & 63) == 0) red[threadIdx.x >> 6] = pre;
    __syncthreads();
    int total = red[0] + red[1] + red[2] + red[3];
    int i = blockIdx.x * 256 + threadIdx.x;
    if (i < N_NODES) offsets[i + 1] = incl[i] + total;
    if (i == 0) offsets[0] = 0;
}

// atomic-free scatter using precomputed rank
__global__ void scatter_kernel(const int* __restrict__ ei, int E,
                               const int* __restrict__ offsets,
                               const int* __restrict__ rank,
                               int* __restrict__ srcs)
{
    int e = blockIdx.x * blockDim.x + threadIdx.x;
    if (e >= E) return;
    int s = ei[e], d = ei[E + e];
    srcs[offsets[d] + rank[e]] = s;
}

// ---------------- layer 1 gather: one wave per dst node (fp8 h rows) --------
// 128-thread blocks (2 waves). Output h1 stored as PACKED BF16 (uint2/lane).
__global__ void gather1_kernel(const uint32* __restrict__ h8,   // N x 32 dwords
                               const float* __restrict__ ssrc,
                               const float* __restrict__ sdst,
                               const int* __restrict__ offsets,
                               const int* __restrict__ srcs,
                               const float* __restrict__ b1,
                               uint32* __restrict__ h1b)        // N x 64 dwords
{
    __shared__ uint2 sw[2][64];
    int d = (blockIdx.x * blockDim.x + threadIdx.x) >> 6;
    int lane = threadIdx.x & 63;
    int wid = (threadIdx.x >> 6) & 1;
    if (d >= N_NODES) return;
    const int hw = lane & 7;            // head in weight phase
    const int half = lane >> 5;         // edge parity in accumulate phase
    const int u = lane & 31;            // dword in row: channels 4u..4u+3
    const int hc = u >> 2;              // head of my channels
    const float sd_w = sdst[d * H1 + hw];

    float acc0 = 0.f, acc1 = 0.f, acc2 = 0.f, acc3 = 0.f;
    float wsum = 0.f;

    // self-loop weight for my channel head
    float lgs = ssrc[d * H1 + hc] + sdst[d * H1 + hc];
    lgs = lgs >= 0.f ? lgs : NEG * lgs;
    const float ws_self = __expf(lgs);
    {   // only half 0 accumulates the self row (avoid double count)
        float m = (half == 0) ? ws_self : 0.f;
        uint32 p = h8[(size_t)d * 32 + u];
        v2f lo = __builtin_amdgcn_cvt_pk_f32_fp8((int)p, false);
        v2f hi = __builtin_amdgcn_cvt_pk_f32_fp8((int)p, true);
        acc0 = m * lo[0]; acc1 = m * lo[1];
        acc2 = m * hi[0]; acc3 = m * hi[1];
    }

    // (s,w) staging slot for my (half, head): read swp[16*t] = edge 2t+half
    const uint2* swp = &sw[wid][(half << 3) | hc];
    const int beg = offsets[d], end = offsets[d + 1];
    for (int base = beg; base < end; base += 8) {
        int cnt = end - base; if (cnt > 8) cnt = 8;
        int s_l = 0; float w_l = 0.f;
        if ((lane >> 3) < cnt) {
            s_l = srcs[base + (lane >> 3)];
            float lg = ssrc[s_l * H1 + hw] + sd_w;
            lg = lg >= 0.f ? lg : NEG * lg;
            w_l = __expf(lg);
        }
        wsum += w_l;
        sw[wid][lane] = make_uint2((uint32)s_l, __float_as_uint(w_l));
        asm volatile("s_waitcnt lgkmcnt(0)" ::: "memory");
#pragma unroll
        for (int t = 0; t < 4; ++t) {       // slots >= cnt carry w=0, s=0
            uint2 q = swp[16 * t];
            float w = __uint_as_float(q.y);
            uint32 p = h8[(size_t)q.x * 32 + u];
            v2f lo = __builtin_amdgcn_cvt_pk_f32_fp8((int)p, false);
            v2f hi = __builtin_amdgcn_cvt_pk_f32_fp8((int)p, true);
            acc0 = fmaf(w, lo[0], acc0);
            acc1 = fmaf(w, lo[1], acc1);
            acc2 = fmaf(w, hi[0], acc2);
            acc3 = fmaf(w, hi[1], acc3);
        }
    }
    // head-wise total: sum wsum over the 8 edge-slot groups (xor bits 3..5)
    wsum += __shfl_xor(wsum, 8);
    wsum += __shfl_xor(wsum, 16);
    wsum += __shfl_xor(wsum, 32);
    float ws = ws_self + __shfl(wsum, hc);
    // cross-half accumulator reduce
    acc0 += __shfl_xor(acc0, 32);
    acc1 += __shfl_xor(acc1, 32);
    acc2 += __shfl_xor(acc2, 32);
    acc3 += __shfl_xor(acc3, 32);
    if (half == 0) {
        float inv = 1.f / (ws + 1e-16f);
        float4 bb = ((const float4*)b1)[u];
        float4 r;
        r.x = fmaf(acc0, inv, bb.x); r.x = r.x > 0.f ? r.x : 0.f;
        r.y = fmaf(acc1, inv, bb.y); r.y = r.y > 0.f ? r.y : 0.f;
        r.z = fmaf(acc2, inv, bb.z); r.z = r.z > 0.f ? r.z : 0.f;
        r.w = fmaf(acc3, inv, bb.w); r.w = r.w > 0.f ? r.w : 0.f;
        uint32 p0 = ((uint32)f2bf(r.y) << 16) | (uint32)f2bf(r.x);
        uint32 p1 = ((uint32)f2bf(r.w) << 16) | (uint32)f2bf(r.z);
        ((uint2*)(h1b + (size_t)d * 64))[u] = make_uint2(p0, p1);
    }
}

// ---------------- layer 2 GEMM (bf16 MFMA) + logits, fused ------------------
// A frags = direct uint4 loads from packed-bf16 h1b; B = W2^T bf16 [48][136]
// in LDS. Output h2 packed to FP8 (4MB table -> fits per-XCD L2, so gather2's
// random row reads become L2 hits). Logits from MFMA accs via butterflies.
__global__ __launch_bounds__(256) void gemm2_kernel(
    const uint32* __restrict__ h1b, const unsigned short* __restrict__ w2t,
    uint32* __restrict__ h2f8,          // fp8 rows, N x 10 dwords
    const float* __restrict__ a_src, const float* __restrict__ a_dst,
    float* __restrict__ ssrc, float* __restrict__ sdst)
{
    __shared__ __align__(16) unsigned short w2s[6528];   // 13056 B
    const int row0 = blockIdx.x * 64;
    const int tid = threadIdx.x;
    const int wid = tid >> 6, lane = tid & 63;
    const int bc = lane & 15, g = lane >> 4;

    // ---- stage W2^T bf16 (3264 dwords) ----
    {
        const uint32* gs = (const uint32*)w2t;
        uint32* wsd = (uint32*)w2s;
        for (int i = tid; i < 3264; i += 256) wsd[i] = gs[i];
    }
    // ---- A fragments: wave w owns rows 16w..16w+15, direct bf16 loads ----
    const int arow = row0 + wid * 16 + bc;
    const bool rowok = arow < N_NODES;
    bf16x8 a[4];
#pragma unroll
    for (int s = 0; s < 4; ++s) {
        uint4 v = make_uint4(0u, 0u, 0u, 0u);
        if (rowok) v = *(const uint4*)&h1b[(size_t)arow * 64 + 16 * s + 4 * g];
        a[s] = *(bf16x8*)&v;
    }
    __syncthreads();
    // ---- 4 k-steps x 3 col-fragments = 12 MFMA / wave ----
    f32x4 acc[3];
#pragma unroll
    for (int j = 0; j < 3; ++j)
#pragma unroll
        for (int r = 0; r < 4; ++r) acc[j][r] = 0.f;
#pragma unroll
    for (int s = 0; s < 4; ++s) {
#pragma unroll
        for (int j = 0; j < 3; ++j) {
            bf16x8 b = *(const bf16x8*)&w2s[(16 * j + bc) * 136 + 32 * s + 8 * g];
            acc[j] = __builtin_amdgcn_mfma_f32_16x16x32_bf16(a[s], b, acc[j], 0, 0, 0);
        }
    }
    // ---- h2 fp8 pack: channels 4k..4k+3 live in adjacent bc-lanes ----
    const int cr0 = wid * 16 + 4 * g;
#pragma unroll
    for (int j = 0; j < 3; ++j)
#pragma unroll
        for (int r = 0; r < 4; ++r) {
            float v0 = acc[j][r];
            float v1 = __shfl_xor(v0, 1);
            float v2 = __shfl_xor(v0, 2);
            float v3 = __shfl_xor(v0, 3);
            if ((bc & 3) == 0) {
                int dw = 4 * j + (bc >> 2);          // dword index in row
                int row = row0 + cr0 + r;
                if (dw < 10 && row < N_NODES) {
                    int p = __builtin_amdgcn_cvt_pk_fp8_f32(v0, v1, 0, false);
                    p     = __builtin_amdgcn_cvt_pk_fp8_f32(v2, v3, p, true);
                    h2f8[(size_t)row * 10 + dw] = (uint32)p;
                }
            }
        }
    // ---- logits via bc-butterflies: 16 bc-lanes hold all cols of 4 rows ----
    float avs[3], avd[3];
#pragma unroll
    for (int j = 0; j < 3; ++j) {
        int col = 16 * j + bc;
        avs[j] = (col < NCLS) ? a_src[col] : 0.f;
        avd[j] = (col < NCLS) ? a_dst[col] : 0.f;
    }
    float ps[4], pd[4];
#pragma unroll
    for (int r = 0; r < 4; ++r) {
        float s_ = acc[0][r] * avs[0];
        s_ = fmaf(acc[1][r], avs[1], s_);
        s_ = fmaf(acc[2][r], avs[2], s_);
        float d_ = acc[0][r] * avd[0];
        d_ = fmaf(acc[1][r], avd[1], d_);
        d_ = fmaf(acc[2][r], avd[2], d_);
        ps[r] = s_; pd[r] = d_;
    }
#pragma unroll
    for (int o = 1; o < 16; o <<= 1) {
#pragma unroll
        for (int r = 0; r < 4; ++r) {
            ps[r] += __shfl_xor(ps[r], o);
            pd[r] += __shfl_xor(pd[r], o);
        }
    }
    if (bc < 4) {
        int row = row0 + cr0 + bc;
        if (row < N_NODES) {
            float vs = bc == 0 ? ps[0] : bc == 1 ? ps[1] : bc == 2 ? ps[2] : ps[3];
            float vd = bc == 0 ? pd[0] : bc == 1 ? pd[1] : bc == 2 ? pd[2] : pd[3];
            ssrc[row] = vs;
            sdst[row] = vd;
        }
    }
}

// ---------------- layer 2 gather + log_softmax: one wave per node (fp8) -----
// 128-thread blocks (2 waves). h2 rows are fp8 (10 dwords): 4MB table is
// per-XCD-L2-resident -> random reads hit L2.
__global__ void gather2_kernel(const uint32* __restrict__ h2f8, // N x 10 dwords
                               const float* __restrict__ ssrc,
                               const float* __restrict__ sdst,
                               const int* __restrict__ offsets,
                               const int* __restrict__ srcs,
                               const float* __restrict__ b2,
                               float* __restrict__ out)
{
    __shared__ uint2 sw[2][64];
    __shared__ __align__(16) float4 pacc[2][64];
    int d = (blockIdx.x * blockDim.x + threadIdx.x) >> 6;
    int lane = threadIdx.x & 63;
    int wid = (threadIdx.x >> 6) & 1;
    if (d >= N_NODES) return;
    const float sd = sdst[d];
    const int g = lane / 10;              // group 0..6 (g<6 accumulate)
    const int c = lane - 10 * g;          // dword within row: channels 4c..4c+3
    const bool act = lane < 10;           // lanes that own the output
    float acc0 = 0.f, acc1 = 0.f, acc2 = 0.f, acc3 = 0.f, wl = 0.f;

    // self-loop (output lanes only)
    float ws_self;
    {
        float lg = ssrc[d] + sd; lg = lg >= 0.f ? lg : NEG * lg;
        ws_self = __expf(lg);
        if (act) {
            uint32 p = h2f8[(size_t)d * 10 + lane];
            v2f lo = __builtin_amdgcn_cvt_pk_f32_fp8((int)p, false);
            v2f hi = __builtin_amdgcn_cvt_pk_f32_fp8((int)p, true);
            acc0 = ws_self * lo[0]; acc1 = ws_self * lo[1];
            acc2 = ws_self * hi[0]; acc3 = ws_self * hi[1];
        }
    }
    const int beg = offsets[d], end = offsets[d + 1];
    for (int base = beg; base < end; base += 64) {
        int cnt = end - base; if (cnt > 64) cnt = 64;
        int s_l = 0; float w_l = 0.f;
        if (lane < cnt) {
            s_l = srcs[base + lane];
            float lg = ssrc[s_l] + sd; lg = lg >= 0.f ? lg : NEG * lg;
            w_l = __expf(lg);
        }
        wl += w_l;
        sw[wid][lane] = make_uint2((uint32)s_l, __float_as_uint(w_l));
        asm volatile("s_waitcnt lgkmcnt(0)" ::: "memory");
        for (int j = 0; j < cnt; j += 6) {
            int jj = j + g;
            uint2 q = sw[wid][jj & 63];
            float w = ((g < 6) & (jj < cnt)) ? __uint_as_float(q.y) : 0.f;
            uint32 p = h2f8[(size_t)q.x * 10 + c];
            v2f lo = __builtin_amdgcn_cvt_pk_f32_fp8((int)p, false);
            v2f hi = __builtin_amdgcn_cvt_pk_f32_fp8((int)p, true);
            acc0 = fmaf(w, lo[0], acc0);
            acc1 = fmaf(w, lo[1], acc1);
            acc2 = fmaf(w, hi[0], acc2);
            acc3 = fmaf(w, hi[1], acc3);
        }
    }
    // denominator: one full-wave reduce at the end
    float t = wl;
#pragma unroll
    for (int o = 32; o > 0; o >>= 1) t += __shfl_xor(t, o);
    float ws = ws_self + t;
    // cross-group accumulator reduce via LDS (partials at lanes c + 10k)
    float4 mine; mine.x = acc0; mine.y = acc1; mine.z = acc2; mine.w = acc3;
    pacc[wid][lane] = mine;
    asm volatile("s_waitcnt lgkmcnt(0)" ::: "memory");
    float l0 = -INFINITY, l1 = -INFINITY, l2 = -INFINITY, l3 = -INFINITY;
    if (act) {
        float4 s0 = pacc[wid][lane];
        float4 s1 = pacc[wid][lane + 10];
        float4 s2 = pacc[wid][lane + 20];
        float4 s3 = pacc[wid][lane + 30];
        float4 s4 = pacc[wid][lane + 40];
        float4 s5 = pacc[wid][lane + 50];
        float a0 = s0.x + s1.x + s2.x + s3.x + s4.x + s5.x;
        float a1 = s0.y + s1.y + s2.y + s3.y + s4.y + s5.y;
        float a2 = s0.z + s1.z + s2.z + s3.z + s4.z + s5.z;
        float a3 = s0.w + s1.w + s2.w + s3.w + s4.w + s5.w;
        float inv = 1.f / (ws + 1e-16f);
        l0 = fmaf(a0, inv, b2[4 * lane + 0]);
        l1 = fmaf(a1, inv, b2[4 * lane + 1]);
        l2 = fmaf(a2, inv, b2[4 * lane + 2]);
        l3 = fmaf(a3, inv, b2[4 * lane + 3]);
    }
    // softmax over 10 active lanes: 16-lane butterflies suffice
    float m = fmaxf(fmaxf(l0, l1), fmaxf(l2, l3));
#pragma unroll
    for (int o = 8; o > 0; o >>= 1) m = fmaxf(m, __shfl_xor(m, o));
    float ex = act ? (__expf(l0 - m) + __expf(l1 - m) + __expf(l2 - m) + __expf(l3 - m)) : 0.f;
#pragma unroll
    for (int o = 8; o > 0; o >>= 1) ex += __shfl_xor(ex, o);
    float lse = __logf(ex) + m;
    if (act) {
        float4 r;
        r.x = l0 - lse; r.y = l1 - lse; r.z = l2 - lse; r.w = l3 - lse;
        ((float4*)(out + (size_t)d * NCLS))[lane] = r;
    }
}

extern "C" void kernel_launch(void* const* d_in, const int* in_sizes, int n_in,
                              void* d_out, int out_size, void* d_ws, size_t ws_size,
                              hipStream_t stream)
{
    const float* x   = (const float*)d_in[0];
    const int*   ei  = (const int*)  d_in[1];
    const float* W1  = (const float*)d_in[2];
    const float* as1 = (const float*)d_in[3];
    const float* ad1 = (const float*)d_in[4];
    const float* b1  = (const float*)d_in[5];
    const float* W2  = (const float*)d_in[6];
    const float* as2 = (const float*)d_in[7];
    const float* ad2 = (const float*)d_in[8];
    const float* b2  = (const float*)d_in[9];
    float* out = (float*)d_out;
    const int E = in_sizes[1] / 2;

    float* ws = (float*)d_ws;
    size_t off = 0;
    uint32* h1f8 = (uint32*)(ws + off); off += (size_t)N_NODES * 32;  // fp8 N x 128
    uint32* h1b = (uint32*)(ws + off); off += (size_t)N_NODES * 64;   // bf16 N x 128 packed
    float* ss1  = ws + off; off += (size_t)N_NODES * H1;
    float* sd1  = ws + off; off += (size_t)N_NODES * H1;
    uint32* h2f8 = (uint32*)(ws + off); off += (size_t)N_NODES * 10;  // fp8 N x 40
    float* ss2  = ws + off; off += N_NODES;
    float* sd2  = ws + off; off += N_NODES;
    unsigned short* w1t = (unsigned short*)(ws + off); off += 8704;   // bf16 W1^T [128][136]
    unsigned short* w2t = (unsigned short*)(ws + off); off += 3264;   // bf16 W2^T [48][136]
    int* ib = (int*)(ws + off);
    size_t ioff = 0;
    int* deg     = ib + ioff; ioff += N_NODES;      // zeroed in prep_w_kernel
    int* incl    = ib + ioff; ioff += N_NODES;
    int* offsets = ib + ioff; ioff += N_NODES + 1;
    int* bsum    = ib + ioff; ioff += 512;
    int* rank    = ib + ioff; ioff += E;
    int* srcs    = ib + ioff; ioff += E;

    const int nb = (N_NODES + 255) / 256;           // 391
    const int nc = (E + 255) / 256;                 // count blocks (6250)

    // W1/W2 -> bf16 transposed+padded + deg zeroing
    prep_w_kernel<<<nb, 256, 0, stream>>>(W1, W2, w1t, w2t, deg);

    // fused layer-1 MFMA gemm(+logits) + CSR count (proven 1:4 interleave)
    gemm1_count_kernel<<<NG + nc, 256, 0, stream>>>(x, w1t, h1f8, as1, ad1,
                                                    ss1, sd1, ei, E, deg, rank);
    // CSR finish
    scan1_kernel<<<nb, 256, 0, stream>>>(deg, incl, bsum);
    scan3_kernel<<<nb, 256, 0, stream>>>(incl, bsum, offsets);
    scatter_kernel<<<(E + 255) / 256, 256, 0, stream>>>(ei, E, offsets, rank, srcs);

    // layer 1 gather (128-thread blocks, bf16-packed output)
    gather1_kernel<<<(N_NODES * 64 + 127) / 128, 128, 0, stream>>>(h1f8, ss1, sd1, offsets, srcs, b1, h1b);

    // layer 2 (MFMA gemm + fp8 h2 pack + shuffle logits fused)
    gemm2_kernel<<<(N_NODES + 63) / 64, 256, 0, stream>>>(h1b, w2t, h2f8, as2, ad2, ss2, sd2);
    gather2_kernel<<<(N_NODES * 64 + 127) / 128, 128, 0, stream>>>(h2f8, ss2, sd2, offsets, srcs, b2, out);
}